// Round 4
// baseline (2122.854 us; speedup 1.0000x reference)
//
#include <hip/hip_runtime.h>
#include <stdint.h>

#define N_NODES 100000
#define N_EDGES 1600000
#define HDIM    128
#define G_GRAPHS 64
#define NTOT (N_EDGES + N_NODES)
#define SCAN_NB ((N_NODES + 2047) / 2048)   // 49

static_assert(N_NODES % 16 == 0, "tile");
static_assert(SCAN_NB <= 64, "scan2 single wave");

// ---- degree (weighted) + in-edge count histogram ----
__global__ void k_deg_cnt(const int* __restrict__ ei, const float* __restrict__ ew,
                          float* __restrict__ deg, int* __restrict__ cnt) {
    int e = blockIdx.x * 256 + threadIdx.x;
    if (e >= N_EDGES) return;
    int dst = ei[N_EDGES + e];
    atomicAdd(&deg[dst], ew[e]);
    atomicAdd(&cnt[dst], 1);
}

// ---- dinv = rsqrt(deg + 1)  (self-loop weight 1 -> deg always > 0) ----
__global__ void k_dinv(const float* __restrict__ deg, float* __restrict__ dinv) {
    int i = blockIdx.x * 256 + threadIdx.x;
    if (i >= N_NODES) return;
    dinv[i] = 1.0f / sqrtf(deg[i] + 1.0f);
}

// ---- exclusive scan of (cnt[i]+1), 3 phases ----
__global__ void k_scan1(const int* __restrict__ cnt, int* __restrict__ partial) {
    int tid = threadIdx.x;
    int base = blockIdx.x * 2048 + tid * 8;
    int s = 0;
#pragma unroll
    for (int j = 0; j < 8; j++) {
        int i = base + j;
        if (i < N_NODES) s += cnt[i] + 1;
    }
    for (int off = 32; off; off >>= 1) s += __shfl_down(s, off);
    __shared__ int sw[4];
    if ((tid & 63) == 0) sw[tid >> 6] = s;
    __syncthreads();
    if (tid == 0) partial[blockIdx.x] = sw[0] + sw[1] + sw[2] + sw[3];
}

__global__ void k_scan2(int* __restrict__ partial) {
    int lane = threadIdx.x;
    int v = (lane < SCAN_NB) ? partial[lane] : 0;
    int orig = v;
    for (int off = 1; off < 64; off <<= 1) {
        int u = __shfl_up(v, off);
        if (lane >= off) v += u;
    }
    if (lane < SCAN_NB) partial[lane] = v - orig;   // exclusive
}

__global__ void k_scan3(const int* __restrict__ cnt, const int* __restrict__ partial,
                        int* __restrict__ offs) {
    int tid = threadIdx.x;
    int base = blockIdx.x * 2048 + tid * 8;
    int vals[8];
    int tsum = 0;
#pragma unroll
    for (int j = 0; j < 8; j++) {
        int i = base + j;
        vals[j] = (i < N_NODES) ? cnt[i] + 1 : 0;
        tsum += vals[j];
    }
    __shared__ int s[256];
    s[tid] = tsum;
    __syncthreads();
    for (int off = 1; off < 256; off <<= 1) {
        int v = 0;
        if (tid >= off) v = s[tid - off];
        __syncthreads();
        s[tid] += v;
        __syncthreads();
    }
    int run = partial[blockIdx.x] + s[tid] - tsum;   // block base + thread-exclusive
#pragma unroll
    for (int j = 0; j < 8; j++) {
        int i = base + j;
        if (i < N_NODES) offs[i] = run;
        run += vals[j];
    }
}

// ---- fill CSR (grouped by dst), includes self loops; entry = (src, norm) ----
__global__ void k_fill(const int* __restrict__ ei, const float* __restrict__ ew,
                       const float* __restrict__ dinv, const int* __restrict__ offs,
                       int* __restrict__ fill, int2* __restrict__ csr) {
    int e = blockIdx.x * 256 + threadIdx.x;
    if (e < N_EDGES) {
        int src = ei[e];
        int dst = ei[N_EDGES + e];
        float nrm = dinv[src] * ew[e] * dinv[dst];
        int p = offs[dst] + atomicAdd(&fill[dst], 1);
        csr[p] = make_int2(src, __float_as_int(nrm));
    } else if (e < NTOT) {
        int i = e - N_EDGES;
        float d = dinv[i];
        int p = offs[i] + atomicAdd(&fill[i], 1);
        csr[p] = make_int2(i, __float_as_int(d * d));
    }
}

// ---- dense transform t = h @ W (W f32 staged in LDS) ----
__global__ __launch_bounds__(256) void k_transform(const float* __restrict__ hin,
                                                   const float* __restrict__ Wg,
                                                   float* __restrict__ t) {
    __shared__ float Wl[HDIM * HDIM];     // 64 KB
    __shared__ float hl[16 * 129];        // padded rows
    int tid = threadIdx.x;
    const float4* W4 = (const float4*)Wg;  // 4096 float4
#pragma unroll
    for (int i = tid; i < 4096; i += 256) {
        float4 v = W4[i];
        int b = i * 4;
        Wl[b + 0] = v.x; Wl[b + 1] = v.y; Wl[b + 2] = v.z; Wl[b + 3] = v.w;
    }
    __syncthreads();
    int ty = tid >> 4, tx = tid & 15;
    for (int tile = blockIdx.x; tile < N_NODES / 16; tile += gridDim.x) {
        int r = tile * 16 + ty;
        float* hp = &hl[ty * 129 + tx * 8];
        const float4* h4 = (const float4*)&hin[(size_t)r * HDIM + tx * 8];
        float4 a = h4[0], b = h4[1];
        hp[0] = a.x; hp[1] = a.y; hp[2] = a.z; hp[3] = a.w;
        hp[4] = b.x; hp[5] = b.y; hp[6] = b.z; hp[7] = b.w;
        __syncthreads();
        float acc[8];
#pragma unroll
        for (int j = 0; j < 8; j++) acc[j] = 0.f;
        const float* hrow = &hl[ty * 129];
#pragma unroll 4
        for (int k = 0; k < HDIM; k++) {
            float av = hrow[k];
            const float4* wr = (const float4*)&Wl[k * HDIM + tx * 8];
            float4 b0 = wr[0], b1 = wr[1];
            acc[0] += av * b0.x; acc[1] += av * b0.y; acc[2] += av * b0.z; acc[3] += av * b0.w;
            acc[4] += av * b1.x; acc[5] += av * b1.y; acc[6] += av * b1.z; acc[7] += av * b1.w;
        }
        float4* t4 = (float4*)&t[(size_t)r * HDIM + tx * 8];
        t4[0] = make_float4(acc[0], acc[1], acc[2], acc[3]);
        t4[1] = make_float4(acc[4], acc[5], acc[6], acc[7]);
        __syncthreads();
    }
}

// ---- aggregation: one wave per node, lane holds float2 of H; + bias + relu ----
// POOL=1 (last layer): skip the h store; instead dot with lin_w, wave-reduce,
// one scalar atomic per node into pooledS[batch[node]].
template <int POOL>
__global__ void k_aggregate(const float* __restrict__ t, const int* __restrict__ offs,
                            const int* __restrict__ cnt, const int2* __restrict__ csr,
                            const float* __restrict__ bias, float* __restrict__ hout,
                            const float* __restrict__ lw, const int* __restrict__ batch,
                            float* __restrict__ pooledS) {
    int tid = threadIdx.x;
    int node = blockIdx.x * 4 + (tid >> 6);
    int lane = tid & 63;
    if (node >= N_NODES) return;
    int beg = offs[node];
    int num = cnt[node] + 1;
    const float2* t2 = (const float2*)t;
    float ax = 0.f, ay = 0.f;
    for (int j = 0; j < num; j++) {
        int2 sw = csr[beg + j];
        float w = __int_as_float(sw.y);
        float2 v = t2[(size_t)sw.x * 64 + lane];
        ax += w * v.x;
        ay += w * v.y;
    }
    float2 bb = ((const float2*)bias)[lane];
    ax = fmaxf(ax + bb.x, 0.f);
    ay = fmaxf(ay + bb.y, 0.f);
    if (POOL) {
        float2 wv = ((const float2*)lw)[lane];
        float d = ax * wv.x + ay * wv.y;
        for (int off = 32; off; off >>= 1) d += __shfl_down(d, off);
        if (lane == 0) atomicAdd(&pooledS[batch[node]], d);
    } else {
        ((float2*)hout)[(size_t)node * 64 + lane] = make_float2(ax, ay);
    }
}

// ---- final: out[g] = pooledS[g]/cnt_g + lb  (batch sorted -> binary search) ----
__global__ void k_final(const float* __restrict__ pooledS, const int* __restrict__ batch,
                        const float* __restrict__ lb, float* __restrict__ out) {
    int g = threadIdx.x;   // 64 threads
    int lo = 0, hi = N_NODES;
    while (lo < hi) { int m = (lo + hi) >> 1; if (batch[m] < g) lo = m + 1; else hi = m; }
    int beg = lo;
    hi = N_NODES;
    while (lo < hi) { int m = (lo + hi) >> 1; if (batch[m] < g + 1) lo = m + 1; else hi = m; }
    float c = fmaxf((float)(lo - beg), 1.0f);
    out[g] = pooledS[g] / c + lb[0];
}

extern "C" void kernel_launch(void* const* d_in, const int* in_sizes, int n_in,
                              void* d_out, int out_size, void* d_ws, size_t ws_size,
                              hipStream_t stream) {
    const float* x   = (const float*)d_in[0];
    const float* ew  = (const float*)d_in[1];
    const int*   ei  = (const int*)d_in[2];
    const int*   bat = (const int*)d_in[3];
    const float* W1  = (const float*)d_in[4];
    const float* b1  = (const float*)d_in[5];
    const float* W2  = (const float*)d_in[6];
    const float* b2  = (const float*)d_in[7];
    const float* W3  = (const float*)d_in[8];
    const float* b3  = (const float*)d_in[9];
    const float* lw  = (const float*)d_in[10];
    const float* lb  = (const float*)d_in[11];
    float* out = (float*)d_out;

    char* w = (char*)d_ws;
    size_t o = 0;
    auto carve = [&](size_t bytes) -> void* {
        void* p = w + o;
        o = (o + bytes + 255) & ~(size_t)255;
        return p;
    };
    float* deg     = (float*)carve((size_t)N_NODES * 4);
    int*   cnt     = (int*)  carve((size_t)N_NODES * 4);
    int*   fill    = (int*)  carve((size_t)N_NODES * 4);
    float* pooledS = (float*)carve((size_t)G_GRAPHS * 4);
    char*  zero1_end = w + o;                     // deg..pooledS span
    float* dinv  = (float*)carve((size_t)N_NODES * 4);
    int*   offs  = (int*)  carve((size_t)N_NODES * 4);
    int*   part  = (int*)  carve(64 * 4);
    int2*  csr   = (int2*) carve((size_t)NTOT * 8);
    float* t     = (float*)carve((size_t)N_NODES * HDIM * 4);
    float* h     = (float*)carve((size_t)N_NODES * HDIM * 4);
    (void)ws_size; (void)in_sizes; (void)n_in; (void)out_size;

    hipMemsetAsync(deg, 0, (size_t)(zero1_end - (char*)deg), stream);

    k_deg_cnt<<<(N_EDGES + 255) / 256, 256, 0, stream>>>(ei, ew, deg, cnt);
    k_dinv<<<(N_NODES + 255) / 256, 256, 0, stream>>>(deg, dinv);
    k_scan1<<<SCAN_NB, 256, 0, stream>>>(cnt, part);
    k_scan2<<<1, 64, 0, stream>>>(part);
    k_scan3<<<SCAN_NB, 256, 0, stream>>>(cnt, part, offs);
    k_fill<<<(NTOT + 255) / 256, 256, 0, stream>>>(ei, ew, dinv, offs, fill, csr);

    k_transform<<<512, 256, 0, stream>>>(x, W1, t);
    k_aggregate<0><<<N_NODES / 4, 256, 0, stream>>>(t, offs, cnt, csr, b1, h, lw, bat, pooledS);
    k_transform<<<512, 256, 0, stream>>>(h, W2, t);
    k_aggregate<0><<<N_NODES / 4, 256, 0, stream>>>(t, offs, cnt, csr, b2, h, lw, bat, pooledS);
    k_transform<<<512, 256, 0, stream>>>(h, W3, t);
    k_aggregate<1><<<N_NODES / 4, 256, 0, stream>>>(t, offs, cnt, csr, b3, nullptr, lw, bat, pooledS);

    k_final<<<1, G_GRAPHS, 0, stream>>>(pooledS, bat, lb, out);
}

// Round 5
// 1083.241 us; speedup vs baseline: 1.9597x; 1.9597x over previous
//
#include <hip/hip_runtime.h>
#include <stdint.h>

#define N_NODES 100000
#define N_EDGES 1600000
#define HDIM    128
#define G_GRAPHS 64
#define NTOT (N_EDGES + N_NODES)
#define SCAN_NB ((N_NODES + 2047) / 2048)   // 49
#define PSLOTS 64

static_assert(N_NODES % 16 == 0, "tile");
static_assert(SCAN_NB <= 64, "scan2 single wave");

// ---- degree (weighted) + in-edge count histogram ----
__global__ void k_deg_cnt(const int* __restrict__ ei, const float* __restrict__ ew,
                          float* __restrict__ deg, int* __restrict__ cnt) {
    int e = blockIdx.x * 256 + threadIdx.x;
    if (e >= N_EDGES) return;
    int dst = ei[N_EDGES + e];
    atomicAdd(&deg[dst], ew[e]);
    atomicAdd(&cnt[dst], 1);
}

// ---- dinv = rsqrt(deg + 1)  (self-loop weight 1 -> deg always > 0) ----
__global__ void k_dinv(const float* __restrict__ deg, float* __restrict__ dinv) {
    int i = blockIdx.x * 256 + threadIdx.x;
    if (i >= N_NODES) return;
    dinv[i] = 1.0f / sqrtf(deg[i] + 1.0f);
}

// ---- exclusive scan of (cnt[i]+1), 3 phases ----
__global__ void k_scan1(const int* __restrict__ cnt, int* __restrict__ partial) {
    int tid = threadIdx.x;
    int base = blockIdx.x * 2048 + tid * 8;
    int s = 0;
#pragma unroll
    for (int j = 0; j < 8; j++) {
        int i = base + j;
        if (i < N_NODES) s += cnt[i] + 1;
    }
    for (int off = 32; off; off >>= 1) s += __shfl_down(s, off);
    __shared__ int sw[4];
    if ((tid & 63) == 0) sw[tid >> 6] = s;
    __syncthreads();
    if (tid == 0) partial[blockIdx.x] = sw[0] + sw[1] + sw[2] + sw[3];
}

__global__ void k_scan2(int* __restrict__ partial) {
    int lane = threadIdx.x;
    int v = (lane < SCAN_NB) ? partial[lane] : 0;
    int orig = v;
    for (int off = 1; off < 64; off <<= 1) {
        int u = __shfl_up(v, off);
        if (lane >= off) v += u;
    }
    if (lane < SCAN_NB) partial[lane] = v - orig;   // exclusive
}

__global__ void k_scan3(const int* __restrict__ cnt, const int* __restrict__ partial,
                        int* __restrict__ offs) {
    int tid = threadIdx.x;
    int base = blockIdx.x * 2048 + tid * 8;
    int vals[8];
    int tsum = 0;
#pragma unroll
    for (int j = 0; j < 8; j++) {
        int i = base + j;
        vals[j] = (i < N_NODES) ? cnt[i] + 1 : 0;
        tsum += vals[j];
    }
    __shared__ int s[256];
    s[tid] = tsum;
    __syncthreads();
    for (int off = 1; off < 256; off <<= 1) {
        int v = 0;
        if (tid >= off) v = s[tid - off];
        __syncthreads();
        s[tid] += v;
        __syncthreads();
    }
    int run = partial[blockIdx.x] + s[tid] - tsum;   // block base + thread-exclusive
#pragma unroll
    for (int j = 0; j < 8; j++) {
        int i = base + j;
        if (i < N_NODES) offs[i] = run;
        run += vals[j];
    }
}

// ---- fill CSR (grouped by dst), includes self loops; entry = (src, norm) ----
__global__ void k_fill(const int* __restrict__ ei, const float* __restrict__ ew,
                       const float* __restrict__ dinv, const int* __restrict__ offs,
                       int* __restrict__ fill, int2* __restrict__ csr) {
    int e = blockIdx.x * 256 + threadIdx.x;
    if (e < N_EDGES) {
        int src = ei[e];
        int dst = ei[N_EDGES + e];
        float nrm = dinv[src] * ew[e] * dinv[dst];
        int p = offs[dst] + atomicAdd(&fill[dst], 1);
        csr[p] = make_int2(src, __float_as_int(nrm));
    } else if (e < NTOT) {
        int i = e - N_EDGES;
        float d = dinv[i];
        int p = offs[i] + atomicAdd(&fill[i], 1);
        csr[p] = make_int2(i, __float_as_int(d * d));
    }
}

// ---- dense transform t = h @ W (W f32 staged in LDS) ----
__global__ __launch_bounds__(256) void k_transform(const float* __restrict__ hin,
                                                   const float* __restrict__ Wg,
                                                   float* __restrict__ t) {
    __shared__ float Wl[HDIM * HDIM];     // 64 KB
    __shared__ float hl[16 * 129];        // padded rows
    int tid = threadIdx.x;
    const float4* W4 = (const float4*)Wg;  // 4096 float4
#pragma unroll
    for (int i = tid; i < 4096; i += 256) {
        float4 v = W4[i];
        int b = i * 4;
        Wl[b + 0] = v.x; Wl[b + 1] = v.y; Wl[b + 2] = v.z; Wl[b + 3] = v.w;
    }
    __syncthreads();
    int ty = tid >> 4, tx = tid & 15;
    for (int tile = blockIdx.x; tile < N_NODES / 16; tile += gridDim.x) {
        int r = tile * 16 + ty;
        float* hp = &hl[ty * 129 + tx * 8];
        const float4* h4 = (const float4*)&hin[(size_t)r * HDIM + tx * 8];
        float4 a = h4[0], b = h4[1];
        hp[0] = a.x; hp[1] = a.y; hp[2] = a.z; hp[3] = a.w;
        hp[4] = b.x; hp[5] = b.y; hp[6] = b.z; hp[7] = b.w;
        __syncthreads();
        float acc[8];
#pragma unroll
        for (int j = 0; j < 8; j++) acc[j] = 0.f;
        const float* hrow = &hl[ty * 129];
#pragma unroll 4
        for (int k = 0; k < HDIM; k++) {
            float av = hrow[k];
            const float4* wr = (const float4*)&Wl[k * HDIM + tx * 8];
            float4 b0 = wr[0], b1 = wr[1];
            acc[0] += av * b0.x; acc[1] += av * b0.y; acc[2] += av * b0.z; acc[3] += av * b0.w;
            acc[4] += av * b1.x; acc[5] += av * b1.y; acc[6] += av * b1.z; acc[7] += av * b1.w;
        }
        float4* t4 = (float4*)&t[(size_t)r * HDIM + tx * 8];
        t4[0] = make_float4(acc[0], acc[1], acc[2], acc[3]);
        t4[1] = make_float4(acc[4], acc[5], acc[6], acc[7]);
        __syncthreads();
    }
}

// ---- aggregation: one wave per node, lane holds float2 of H; + bias + relu ----
// CSR entries loaded lane-parallel, broadcast via shfl (no per-edge broadcast
// load in the dependent chain). POOL=1: fused dot(lin_w) + spread-slot atomic.
template <int POOL>
__global__ void k_aggregate(const float* __restrict__ t, const int* __restrict__ offs,
                            const int* __restrict__ cnt, const int2* __restrict__ csr,
                            const float* __restrict__ bias, float* __restrict__ hout,
                            const float* __restrict__ lw, const int* __restrict__ batch,
                            float* __restrict__ pp) {
    int tid = threadIdx.x;
    int node = blockIdx.x * 4 + (tid >> 6);
    int lane = tid & 63;
    if (node >= N_NODES) return;
    int beg = offs[node];
    int num = cnt[node] + 1;
    const float2* t2 = (const float2*)t;
    float ax = 0.f, ay = 0.f;
    for (int base = 0; base < num; base += 64) {
        int rem = num - base; if (rem > 64) rem = 64;
        int2 my = make_int2(0, 0);
        if (lane < rem) my = csr[beg + base + lane];
        int   msrc = my.x;
        float mw   = __int_as_float(my.y);
        for (int j = 0; j < rem; j++) {
            int   src = __shfl(msrc, j);
            float w   = __shfl(mw, j);
            float2 v = t2[(size_t)src * 64 + lane];
            ax += w * v.x;
            ay += w * v.y;
        }
    }
    float2 bb = ((const float2*)bias)[lane];
    ax = fmaxf(ax + bb.x, 0.f);
    ay = fmaxf(ay + bb.y, 0.f);
    if (POOL) {
        float2 wv = ((const float2*)lw)[lane];
        float d = ax * wv.x + ay * wv.y;
        for (int off = 32; off; off >>= 1) d += __shfl_down(d, off);
        if (lane == 0)
            atomicAdd(&pp[(blockIdx.x & (PSLOTS - 1)) * G_GRAPHS + batch[node]], d);
    } else {
        ((float2*)hout)[(size_t)node * 64 + lane] = make_float2(ax, ay);
    }
}

// ---- final: out[g] = (sum over slots)/cnt_g + lb ----
__global__ void k_final(const float* __restrict__ pp, const int* __restrict__ batch,
                        const float* __restrict__ lb, float* __restrict__ out) {
    int g = threadIdx.x;   // 64 threads
    float s = 0.f;
#pragma unroll
    for (int k = 0; k < PSLOTS; k++) s += pp[k * G_GRAPHS + g];
    int lo = 0, hi = N_NODES;
    while (lo < hi) { int m = (lo + hi) >> 1; if (batch[m] < g) lo = m + 1; else hi = m; }
    int beg = lo;
    hi = N_NODES;
    while (lo < hi) { int m = (lo + hi) >> 1; if (batch[m] < g + 1) lo = m + 1; else hi = m; }
    float c = fmaxf((float)(lo - beg), 1.0f);
    out[g] = s / c + lb[0];
}

extern "C" void kernel_launch(void* const* d_in, const int* in_sizes, int n_in,
                              void* d_out, int out_size, void* d_ws, size_t ws_size,
                              hipStream_t stream) {
    const float* x   = (const float*)d_in[0];
    const float* ew  = (const float*)d_in[1];
    const int*   ei  = (const int*)d_in[2];
    const int*   bat = (const int*)d_in[3];
    const float* W1  = (const float*)d_in[4];
    const float* b1  = (const float*)d_in[5];
    const float* W2  = (const float*)d_in[6];
    const float* b2  = (const float*)d_in[7];
    const float* W3  = (const float*)d_in[8];
    const float* b3  = (const float*)d_in[9];
    const float* lw  = (const float*)d_in[10];
    const float* lb  = (const float*)d_in[11];
    float* out = (float*)d_out;

    char* w = (char*)d_ws;
    size_t o = 0;
    auto carve = [&](size_t bytes) -> void* {
        void* p = w + o;
        o = (o + bytes + 255) & ~(size_t)255;
        return p;
    };
    float* deg  = (float*)carve((size_t)N_NODES * 4);
    int*   cnt  = (int*)  carve((size_t)N_NODES * 4);
    int*   fill = (int*)  carve((size_t)N_NODES * 4);
    float* pp   = (float*)carve((size_t)PSLOTS * G_GRAPHS * 4);
    char*  zero1_end = w + o;                     // deg..pp span
    float* dinv = (float*)carve((size_t)N_NODES * 4);
    int*   offs = (int*)  carve((size_t)N_NODES * 4);
    int*   part = (int*)  carve(64 * 4);
    int2*  csr  = (int2*) carve((size_t)NTOT * 8);
    float* t    = (float*)carve((size_t)N_NODES * HDIM * 4);
    float* h    = (float*)carve((size_t)N_NODES * HDIM * 4);
    (void)ws_size; (void)in_sizes; (void)n_in; (void)out_size;

    hipMemsetAsync(deg, 0, (size_t)(zero1_end - (char*)deg), stream);

    k_deg_cnt<<<(N_EDGES + 255) / 256, 256, 0, stream>>>(ei, ew, deg, cnt);
    k_dinv<<<(N_NODES + 255) / 256, 256, 0, stream>>>(deg, dinv);
    k_scan1<<<SCAN_NB, 256, 0, stream>>>(cnt, part);
    k_scan2<<<1, 64, 0, stream>>>(part);
    k_scan3<<<SCAN_NB, 256, 0, stream>>>(cnt, part, offs);
    k_fill<<<(NTOT + 255) / 256, 256, 0, stream>>>(ei, ew, dinv, offs, fill, csr);

    k_transform<<<512, 256, 0, stream>>>(x, W1, t);
    k_aggregate<0><<<N_NODES / 4, 256, 0, stream>>>(t, offs, cnt, csr, b1, h, lw, bat, pp);
    k_transform<<<512, 256, 0, stream>>>(h, W2, t);
    k_aggregate<0><<<N_NODES / 4, 256, 0, stream>>>(t, offs, cnt, csr, b2, h, lw, bat, pp);
    k_transform<<<512, 256, 0, stream>>>(h, W3, t);
    k_aggregate<1><<<N_NODES / 4, 256, 0, stream>>>(t, offs, cnt, csr, b3, nullptr, lw, bat, pp);

    k_final<<<1, G_GRAPHS, 0, stream>>>(pp, bat, lb, out);
}

// Round 6
// 922.772 us; speedup vs baseline: 2.3005x; 1.1739x over previous
//
#include <hip/hip_runtime.h>
#include <stdint.h>

#define N_NODES 100000
#define N_EDGES 1600000
#define HDIM    128
#define G_GRAPHS 64
#define NTOT (N_EDGES + N_NODES)
#define SCAN_NB ((N_NODES + 2047) / 2048)   // 49
#define PSLOTS 64

static_assert(N_NODES % 16 == 0, "tile");
static_assert(SCAN_NB <= 64, "scan2 single wave");

__device__ __forceinline__ float bf_lo(uint32_t u) { return __uint_as_float(u << 16); }
__device__ __forceinline__ float bf_hi(uint32_t u) { return __uint_as_float(u & 0xffff0000u); }
__device__ __forceinline__ uint32_t f2bf(float x) {            // RNE f32->bf16
    uint32_t b = __float_as_uint(x);
    return (b + 0x7FFFu + ((b >> 16) & 1u)) >> 16;
}
__device__ __forceinline__ uint32_t pack2(float lo, float hi) {
    return f2bf(lo) | (f2bf(hi) << 16);
}

#define FXSCALE 1099511627776.0f   // 2^40

// ---- one u64 atomic per edge: high16 = count, low48 = fixed-point weight sum.
// Returned old value gives this edge's within-destination sequence number.
__global__ void k_deg_cnt(const int* __restrict__ ei, const float* __restrict__ ew,
                          unsigned long long* __restrict__ packed, uint16_t* __restrict__ seq) {
    int e = blockIdx.x * 256 + threadIdx.x;
    if (e >= N_EDGES) return;
    int dst = ei[N_EDGES + e];
    unsigned long long pk = (1ULL << 48) | (unsigned long long)(ew[e] * FXSCALE);
    unsigned long long old = atomicAdd(&packed[dst], pk);
    seq[e] = (uint16_t)(old >> 48);
}

// ---- unpack: cnt, dinv = rsqrt(deg + 1) ----
__global__ void k_dinv(const unsigned long long* __restrict__ packed,
                       int* __restrict__ cnt, float* __restrict__ dinv) {
    int i = blockIdx.x * 256 + threadIdx.x;
    if (i >= N_NODES) return;
    unsigned long long pk = packed[i];
    cnt[i] = (int)(pk >> 48);
    float deg = (float)(pk & ((1ULL << 48) - 1)) * (1.0f / FXSCALE);
    dinv[i] = 1.0f / sqrtf(deg + 1.0f);
}

// ---- exclusive scan of (cnt[i]+1), 3 phases ----
__global__ void k_scan1(const int* __restrict__ cnt, int* __restrict__ partial) {
    int tid = threadIdx.x;
    int base = blockIdx.x * 2048 + tid * 8;
    int s = 0;
#pragma unroll
    for (int j = 0; j < 8; j++) {
        int i = base + j;
        if (i < N_NODES) s += cnt[i] + 1;
    }
    for (int off = 32; off; off >>= 1) s += __shfl_down(s, off);
    __shared__ int sw[4];
    if ((tid & 63) == 0) sw[tid >> 6] = s;
    __syncthreads();
    if (tid == 0) partial[blockIdx.x] = sw[0] + sw[1] + sw[2] + sw[3];
}

__global__ void k_scan2(int* __restrict__ partial) {
    int lane = threadIdx.x;
    int v = (lane < SCAN_NB) ? partial[lane] : 0;
    int orig = v;
    for (int off = 1; off < 64; off <<= 1) {
        int u = __shfl_up(v, off);
        if (lane >= off) v += u;
    }
    if (lane < SCAN_NB) partial[lane] = v - orig;   // exclusive
}

__global__ void k_scan3(const int* __restrict__ cnt, const int* __restrict__ partial,
                        int* __restrict__ offs) {
    int tid = threadIdx.x;
    int base = blockIdx.x * 2048 + tid * 8;
    int vals[8];
    int tsum = 0;
#pragma unroll
    for (int j = 0; j < 8; j++) {
        int i = base + j;
        vals[j] = (i < N_NODES) ? cnt[i] + 1 : 0;
        tsum += vals[j];
    }
    __shared__ int s[256];
    s[tid] = tsum;
    __syncthreads();
    for (int off = 1; off < 256; off <<= 1) {
        int v = 0;
        if (tid >= off) v = s[tid - off];
        __syncthreads();
        s[tid] += v;
        __syncthreads();
    }
    int run = partial[blockIdx.x] + s[tid] - tsum;   // block base + thread-exclusive
#pragma unroll
    for (int j = 0; j < 8; j++) {
        int i = base + j;
        if (i < N_NODES) offs[i] = run;
        run += vals[j];
    }
}

// ---- fill CSR (grouped by dst) — NO atomics: slot from precomputed seq ----
__global__ void k_fill(const int* __restrict__ ei, const float* __restrict__ ew,
                       const float* __restrict__ dinv, const int* __restrict__ offs,
                       const int* __restrict__ cnt, const uint16_t* __restrict__ seq,
                       int2* __restrict__ csr) {
    int e = blockIdx.x * 256 + threadIdx.x;
    if (e < N_EDGES) {
        int src = ei[e];
        int dst = ei[N_EDGES + e];
        float nrm = dinv[src] * ew[e] * dinv[dst];
        int p = offs[dst] + (int)seq[e];
        csr[p] = make_int2(src, __float_as_int(nrm));
    } else if (e < NTOT) {
        int i = e - N_EDGES;
        float d = dinv[i];
        int p = offs[i] + cnt[i];          // self-loop takes the last slot
        csr[p] = make_int2(i, __float_as_int(d * d));
    }
}

// ---- dense transform t = h @ W; output bf16-packed (dword = 2 cols) ----
__global__ __launch_bounds__(256) void k_transform(const float* __restrict__ hin,
                                                   const float* __restrict__ Wg,
                                                   uint32_t* __restrict__ t) {
    __shared__ float Wl[HDIM * HDIM];     // 64 KB
    __shared__ float hl[16 * 129];        // padded rows
    int tid = threadIdx.x;
    const float4* W4 = (const float4*)Wg;  // 4096 float4
#pragma unroll
    for (int i = tid; i < 4096; i += 256) {
        float4 v = W4[i];
        int b = i * 4;
        Wl[b + 0] = v.x; Wl[b + 1] = v.y; Wl[b + 2] = v.z; Wl[b + 3] = v.w;
    }
    __syncthreads();
    int ty = tid >> 4, tx = tid & 15;
    for (int tile = blockIdx.x; tile < N_NODES / 16; tile += gridDim.x) {
        int r = tile * 16 + ty;
        float* hp = &hl[ty * 129 + tx * 8];
        const float4* h4 = (const float4*)&hin[(size_t)r * HDIM + tx * 8];
        float4 a = h4[0], b = h4[1];
        hp[0] = a.x; hp[1] = a.y; hp[2] = a.z; hp[3] = a.w;
        hp[4] = b.x; hp[5] = b.y; hp[6] = b.z; hp[7] = b.w;
        __syncthreads();
        float acc[8];
#pragma unroll
        for (int j = 0; j < 8; j++) acc[j] = 0.f;
        const float* hrow = &hl[ty * 129];
#pragma unroll 4
        for (int k = 0; k < HDIM; k++) {
            float av = hrow[k];
            const float4* wr = (const float4*)&Wl[k * HDIM + tx * 8];
            float4 b0 = wr[0], b1 = wr[1];
            acc[0] += av * b0.x; acc[1] += av * b0.y; acc[2] += av * b0.z; acc[3] += av * b0.w;
            acc[4] += av * b1.x; acc[5] += av * b1.y; acc[6] += av * b1.z; acc[7] += av * b1.w;
        }
        uint4 pk;
        pk.x = pack2(acc[0], acc[1]);
        pk.y = pack2(acc[2], acc[3]);
        pk.z = pack2(acc[4], acc[5]);
        pk.w = pack2(acc[6], acc[7]);
        ((uint4*)t)[(size_t)r * 16 + tx] = pk;
        __syncthreads();
    }
}

// ---- aggregation: wave per node; lane gathers one bf16x2 dword per edge ----
template <int POOL>
__global__ void k_aggregate(const uint32_t* __restrict__ t, const int* __restrict__ offs,
                            const int* __restrict__ cnt, const int2* __restrict__ csr,
                            const float* __restrict__ bias, float* __restrict__ hout,
                            const float* __restrict__ lw, const int* __restrict__ batch,
                            float* __restrict__ pp) {
    int tid = threadIdx.x;
    int node = blockIdx.x * 4 + (tid >> 6);
    int lane = tid & 63;
    if (node >= N_NODES) return;
    int beg = offs[node];
    int num = cnt[node] + 1;
    float ax = 0.f, ay = 0.f;
    for (int base = 0; base < num; base += 64) {
        int rem = num - base; if (rem > 64) rem = 64;
        int2 my = make_int2(0, 0);
        if (lane < rem) my = csr[beg + base + lane];
        int   msrc = my.x;
        float mw   = __int_as_float(my.y);
        for (int j = 0; j < rem; j++) {
            int   src = __shfl(msrc, j);
            float w   = __shfl(mw, j);
            uint32_t v = t[(size_t)src * 64 + lane];
            ax += w * bf_lo(v);
            ay += w * bf_hi(v);
        }
    }
    float2 bb = ((const float2*)bias)[lane];
    ax = fmaxf(ax + bb.x, 0.f);
    ay = fmaxf(ay + bb.y, 0.f);
    if (POOL) {
        float2 wv = ((const float2*)lw)[lane];
        float d = ax * wv.x + ay * wv.y;
        for (int off = 32; off; off >>= 1) d += __shfl_down(d, off);
        if (lane == 0)
            atomicAdd(&pp[(blockIdx.x & (PSLOTS - 1)) * G_GRAPHS + batch[node]], d);
    } else {
        ((float2*)hout)[(size_t)node * 64 + lane] = make_float2(ax, ay);
    }
}

// ---- final: out[g] = (sum over slots)/cnt_g + lb ----
__global__ void k_final(const float* __restrict__ pp, const int* __restrict__ batch,
                        const float* __restrict__ lb, float* __restrict__ out) {
    int g = threadIdx.x;   // 64 threads
    float s = 0.f;
#pragma unroll
    for (int k = 0; k < PSLOTS; k++) s += pp[k * G_GRAPHS + g];
    int lo = 0, hi = N_NODES;
    while (lo < hi) { int m = (lo + hi) >> 1; if (batch[m] < g) lo = m + 1; else hi = m; }
    int beg = lo;
    hi = N_NODES;
    while (lo < hi) { int m = (lo + hi) >> 1; if (batch[m] < g + 1) lo = m + 1; else hi = m; }
    float c = fmaxf((float)(lo - beg), 1.0f);
    out[g] = s / c + lb[0];
}

extern "C" void kernel_launch(void* const* d_in, const int* in_sizes, int n_in,
                              void* d_out, int out_size, void* d_ws, size_t ws_size,
                              hipStream_t stream) {
    const float* x   = (const float*)d_in[0];
    const float* ew  = (const float*)d_in[1];
    const int*   ei  = (const int*)d_in[2];
    const int*   bat = (const int*)d_in[3];
    const float* W1  = (const float*)d_in[4];
    const float* b1  = (const float*)d_in[5];
    const float* W2  = (const float*)d_in[6];
    const float* b2  = (const float*)d_in[7];
    const float* W3  = (const float*)d_in[8];
    const float* b3  = (const float*)d_in[9];
    const float* lw  = (const float*)d_in[10];
    const float* lb  = (const float*)d_in[11];
    float* out = (float*)d_out;

    char* w = (char*)d_ws;
    size_t o = 0;
    auto carve = [&](size_t bytes) -> void* {
        void* p = w + o;
        o = (o + bytes + 255) & ~(size_t)255;
        return p;
    };
    unsigned long long* packed = (unsigned long long*)carve((size_t)N_NODES * 8);
    float* pp   = (float*)carve((size_t)PSLOTS * G_GRAPHS * 4);
    char*  zero_end = w + o;                      // packed + pp span
    int*      cnt  = (int*)     carve((size_t)N_NODES * 4);
    float*    dinv = (float*)   carve((size_t)N_NODES * 4);
    int*      offs = (int*)     carve((size_t)N_NODES * 4);
    int*      part = (int*)     carve(64 * 4);
    uint16_t* seq  = (uint16_t*)carve((size_t)N_EDGES * 2);
    int2*     csr  = (int2*)    carve((size_t)NTOT * 8);
    uint32_t* t    = (uint32_t*)carve((size_t)N_NODES * 64 * 4);   // bf16x2 dwords
    float*    h    = (float*)   carve((size_t)N_NODES * HDIM * 4);
    (void)ws_size; (void)in_sizes; (void)n_in; (void)out_size;

    hipMemsetAsync(packed, 0, (size_t)(zero_end - (char*)packed), stream);

    k_deg_cnt<<<(N_EDGES + 255) / 256, 256, 0, stream>>>(ei, ew, packed, seq);
    k_dinv<<<(N_NODES + 255) / 256, 256, 0, stream>>>(packed, cnt, dinv);
    k_scan1<<<SCAN_NB, 256, 0, stream>>>(cnt, part);
    k_scan2<<<1, 64, 0, stream>>>(part);
    k_scan3<<<SCAN_NB, 256, 0, stream>>>(cnt, part, offs);
    k_fill<<<(NTOT + 255) / 256, 256, 0, stream>>>(ei, ew, dinv, offs, cnt, seq, csr);

    k_transform<<<512, 256, 0, stream>>>(x, W1, t);
    k_aggregate<0><<<N_NODES / 4, 256, 0, stream>>>(t, offs, cnt, csr, b1, h, lw, bat, pp);
    k_transform<<<512, 256, 0, stream>>>(h, W2, t);
    k_aggregate<0><<<N_NODES / 4, 256, 0, stream>>>(t, offs, cnt, csr, b2, h, lw, bat, pp);
    k_transform<<<512, 256, 0, stream>>>(h, W3, t);
    k_aggregate<1><<<N_NODES / 4, 256, 0, stream>>>(t, offs, cnt, csr, b3, nullptr, lw, bat, pp);

    k_final<<<1, G_GRAPHS, 0, stream>>>(pp, bat, lb, out);
}

// Round 7
// 680.547 us; speedup vs baseline: 3.1193x; 1.3559x over previous
//
#include <hip/hip_runtime.h>
#include <stdint.h>

#define N_NODES 100000
#define N_EDGES 1600000
#define HDIM    128
#define G_GRAPHS 64
#define NTOT (N_EDGES + N_NODES)
#define SCAN_NB ((N_NODES + 2047) / 2048)   // 49
#define PSLOTS 64
#define NSTRIPS (N_NODES / 16)              // 6250

static_assert(N_NODES % 16 == 0, "tile");
static_assert(SCAN_NB <= 64, "scan2 single wave");

typedef __attribute__((ext_vector_type(8))) short bf16x8;
typedef __attribute__((ext_vector_type(4))) float f32x4;

__device__ __forceinline__ float bf_lo(uint32_t u) { return __uint_as_float(u << 16); }
__device__ __forceinline__ float bf_hi(uint32_t u) { return __uint_as_float(u & 0xffff0000u); }
__device__ __forceinline__ uint32_t f2bf(float x) {            // RNE f32->bf16
    uint32_t b = __float_as_uint(x);
    return (b + 0x7FFFu + ((b >> 16) & 1u)) >> 16;
}
__device__ __forceinline__ uint32_t pack2(float lo, float hi) {
    return f2bf(lo) | (f2bf(hi) << 16);
}

#define FXSCALE 1099511627776.0f   // 2^40

// ---- one u64 atomic per edge: high16 = count, low48 = fixed-point weight sum ----
__global__ void k_deg_cnt(const int* __restrict__ ei, const float* __restrict__ ew,
                          unsigned long long* __restrict__ packed, uint16_t* __restrict__ seq) {
    int e = blockIdx.x * 256 + threadIdx.x;
    if (e >= N_EDGES) return;
    int dst = ei[N_EDGES + e];
    unsigned long long pk = (1ULL << 48) | (unsigned long long)(ew[e] * FXSCALE);
    unsigned long long old = atomicAdd(&packed[dst], pk);
    seq[e] = (uint16_t)(old >> 48);
}

// ---- unpack: cnt, dinv = rsqrt(deg + 1) ----
__global__ void k_dinv(const unsigned long long* __restrict__ packed,
                       int* __restrict__ cnt, float* __restrict__ dinv) {
    int i = blockIdx.x * 256 + threadIdx.x;
    if (i >= N_NODES) return;
    unsigned long long pk = packed[i];
    cnt[i] = (int)(pk >> 48);
    float deg = (float)(pk & ((1ULL << 48) - 1)) * (1.0f / FXSCALE);
    dinv[i] = 1.0f / sqrtf(deg + 1.0f);
}

// ---- x f32 -> bf16x2 packed ----
__global__ void k_cvt(const float* __restrict__ x, uint32_t* __restrict__ xb) {
    int i = blockIdx.x * 256 + threadIdx.x;
    if (i >= N_NODES * 64) return;
    float2 v = ((const float2*)x)[i];
    xb[i] = pack2(v.x, v.y);
}

// ---- exclusive scan of (cnt[i]+1), 3 phases ----
__global__ void k_scan1(const int* __restrict__ cnt, int* __restrict__ partial) {
    int tid = threadIdx.x;
    int base = blockIdx.x * 2048 + tid * 8;
    int s = 0;
#pragma unroll
    for (int j = 0; j < 8; j++) {
        int i = base + j;
        if (i < N_NODES) s += cnt[i] + 1;
    }
    for (int off = 32; off; off >>= 1) s += __shfl_down(s, off);
    __shared__ int sw[4];
    if ((tid & 63) == 0) sw[tid >> 6] = s;
    __syncthreads();
    if (tid == 0) partial[blockIdx.x] = sw[0] + sw[1] + sw[2] + sw[3];
}

__global__ void k_scan2(int* __restrict__ partial) {
    int lane = threadIdx.x;
    int v = (lane < SCAN_NB) ? partial[lane] : 0;
    int orig = v;
    for (int off = 1; off < 64; off <<= 1) {
        int u = __shfl_up(v, off);
        if (lane >= off) v += u;
    }
    if (lane < SCAN_NB) partial[lane] = v - orig;   // exclusive
}

__global__ void k_scan3(const int* __restrict__ cnt, const int* __restrict__ partial,
                        int* __restrict__ offs) {
    int tid = threadIdx.x;
    int base = blockIdx.x * 2048 + tid * 8;
    int vals[8];
    int tsum = 0;
#pragma unroll
    for (int j = 0; j < 8; j++) {
        int i = base + j;
        vals[j] = (i < N_NODES) ? cnt[i] + 1 : 0;
        tsum += vals[j];
    }
    __shared__ int s[256];
    s[tid] = tsum;
    __syncthreads();
    for (int off = 1; off < 256; off <<= 1) {
        int v = 0;
        if (tid >= off) v = s[tid - off];
        __syncthreads();
        s[tid] += v;
        __syncthreads();
    }
    int run = partial[blockIdx.x] + s[tid] - tsum;
#pragma unroll
    for (int j = 0; j < 8; j++) {
        int i = base + j;
        if (i < N_NODES) offs[i] = run;
        run += vals[j];
    }
}

// ---- fill CSR (grouped by dst) — no atomics: slot from precomputed seq ----
__global__ void k_fill(const int* __restrict__ ei, const float* __restrict__ ew,
                       const float* __restrict__ dinv, const int* __restrict__ offs,
                       const int* __restrict__ cnt, const uint16_t* __restrict__ seq,
                       int2* __restrict__ csr) {
    int e = blockIdx.x * 256 + threadIdx.x;
    if (e < N_EDGES) {
        int src = ei[e];
        int dst = ei[N_EDGES + e];
        float nrm = dinv[src] * ew[e] * dinv[dst];
        int p = offs[dst] + (int)seq[e];
        csr[p] = make_int2(src, __float_as_int(nrm));
    } else if (e < NTOT) {
        int i = e - N_EDGES;
        float d = dinv[i];
        int p = offs[i] + cnt[i];
        csr[p] = make_int2(i, __float_as_int(d * d));
    }
}

// ---- MFMA transform: t = h @ W, bf16 in/out, f32 accumulate ----
// A-frag: A[m=lane&15][k=quad*8+j]  (uint4 of 8 contiguous bf16 from h row)
// B-frag: B[k=quad*8+j][n=lane&15]  (W pre-swizzled to frag order in LDS)
// D:      col=lane&15, row=quad*4+reg
__global__ __launch_bounds__(256) void k_transform(const uint16_t* __restrict__ hb,
                                                   const float* __restrict__ Wg,
                                                   uint32_t* __restrict__ t) {
    __shared__ uint16_t Wf[16384];    // 32 KB, frag-order bf16
    int tid = threadIdx.x;
    for (int idx = tid; idx < 16384; idx += 256) {
        int k = idx >> 7, n = idx & 127;
        int kc = k >> 5, kq = (k >> 3) & 3, j = k & 7;
        int nt = n >> 4, nl = n & 15;
        Wf[(((kc * 8 + nt) * 64) + kq * 16 + nl) * 8 + j] = (uint16_t)f2bf(Wg[idx]);
    }
    __syncthreads();
    const bf16x8* Wfrag = (const bf16x8*)Wf;
    int lane = tid & 63;
    int quad = lane >> 4;
    int mrow = lane & 15;
    int gwave = blockIdx.x * 4 + (tid >> 6);
    int nwaves = gridDim.x * 4;
    for (int strip = gwave; strip < NSTRIPS; strip += nwaves) {
        const uint16_t* hrow = hb + ((size_t)(strip * 16 + mrow)) * 128 + quad * 8;
        bf16x8 A0 = *(const bf16x8*)(hrow);
        bf16x8 A1 = *(const bf16x8*)(hrow + 32);
        bf16x8 A2 = *(const bf16x8*)(hrow + 64);
        bf16x8 A3 = *(const bf16x8*)(hrow + 96);
        f32x4 acc[8];
#pragma unroll
        for (int nt = 0; nt < 8; nt++) {
            f32x4 a = {0.f, 0.f, 0.f, 0.f};
            a = __builtin_amdgcn_mfma_f32_16x16x32_bf16(A0, Wfrag[(0 * 8 + nt) * 64 + lane], a, 0, 0, 0);
            a = __builtin_amdgcn_mfma_f32_16x16x32_bf16(A1, Wfrag[(1 * 8 + nt) * 64 + lane], a, 0, 0, 0);
            a = __builtin_amdgcn_mfma_f32_16x16x32_bf16(A2, Wfrag[(2 * 8 + nt) * 64 + lane], a, 0, 0, 0);
            a = __builtin_amdgcn_mfma_f32_16x16x32_bf16(A3, Wfrag[(3 * 8 + nt) * 64 + lane], a, 0, 0, 0);
            acc[nt] = a;
        }
#pragma unroll
        for (int nt = 0; nt < 8; nt++) {
#pragma unroll
            for (int r = 0; r < 4; r++) {
                float v = acc[nt][r];
                float nb = __shfl_xor(v, 1);
                if (!(lane & 1)) {
                    int orow = strip * 16 + quad * 4 + r;
                    int oc = (nt * 16 + mrow) >> 1;
                    t[(size_t)orow * 64 + oc] = pack2(v, nb);
                }
            }
        }
    }
}

// ---- aggregation: wave per node; lane gathers one bf16x2 dword per edge ----
// POOL=0: store h bf16-packed. POOL=1: fused dot(lin_w) + spread-slot atomic.
template <int POOL>
__global__ void k_aggregate(const uint32_t* __restrict__ t, const int* __restrict__ offs,
                            const int* __restrict__ cnt, const int2* __restrict__ csr,
                            const float* __restrict__ bias, uint32_t* __restrict__ hout,
                            const float* __restrict__ lw, const int* __restrict__ batch,
                            float* __restrict__ pp) {
    int tid = threadIdx.x;
    int node = blockIdx.x * 4 + (tid >> 6);
    int lane = tid & 63;
    if (node >= N_NODES) return;
    int beg = offs[node];
    int num = cnt[node] + 1;
    float ax = 0.f, ay = 0.f;
    for (int base = 0; base < num; base += 64) {
        int rem = num - base; if (rem > 64) rem = 64;
        int2 my = make_int2(0, 0);
        if (lane < rem) my = csr[beg + base + lane];
        int   msrc = my.x;
        float mw   = __int_as_float(my.y);
        for (int j = 0; j < rem; j++) {
            int   src = __shfl(msrc, j);
            float w   = __shfl(mw, j);
            uint32_t v = t[(size_t)src * 64 + lane];
            ax += w * bf_lo(v);
            ay += w * bf_hi(v);
        }
    }
    float2 bb = ((const float2*)bias)[lane];
    ax = fmaxf(ax + bb.x, 0.f);
    ay = fmaxf(ay + bb.y, 0.f);
    if (POOL) {
        float2 wv = ((const float2*)lw)[lane];
        float d = ax * wv.x + ay * wv.y;
        for (int off = 32; off; off >>= 1) d += __shfl_down(d, off);
        if (lane == 0)
            atomicAdd(&pp[(blockIdx.x & (PSLOTS - 1)) * G_GRAPHS + batch[node]], d);
    } else {
        hout[(size_t)node * 64 + lane] = pack2(ax, ay);
    }
}

// ---- final: out[g] = (sum over slots)/cnt_g + lb ----
__global__ void k_final(const float* __restrict__ pp, const int* __restrict__ batch,
                        const float* __restrict__ lb, float* __restrict__ out) {
    int g = threadIdx.x;   // 64 threads
    float s = 0.f;
#pragma unroll
    for (int k = 0; k < PSLOTS; k++) s += pp[k * G_GRAPHS + g];
    int lo = 0, hi = N_NODES;
    while (lo < hi) { int m = (lo + hi) >> 1; if (batch[m] < g) lo = m + 1; else hi = m; }
    int beg = lo;
    hi = N_NODES;
    while (lo < hi) { int m = (lo + hi) >> 1; if (batch[m] < g + 1) lo = m + 1; else hi = m; }
    float c = fmaxf((float)(lo - beg), 1.0f);
    out[g] = s / c + lb[0];
}

extern "C" void kernel_launch(void* const* d_in, const int* in_sizes, int n_in,
                              void* d_out, int out_size, void* d_ws, size_t ws_size,
                              hipStream_t stream) {
    const float* x   = (const float*)d_in[0];
    const float* ew  = (const float*)d_in[1];
    const int*   ei  = (const int*)d_in[2];
    const int*   bat = (const int*)d_in[3];
    const float* W1  = (const float*)d_in[4];
    const float* b1  = (const float*)d_in[5];
    const float* W2  = (const float*)d_in[6];
    const float* b2  = (const float*)d_in[7];
    const float* W3  = (const float*)d_in[8];
    const float* b3  = (const float*)d_in[9];
    const float* lw  = (const float*)d_in[10];
    const float* lb  = (const float*)d_in[11];
    float* out = (float*)d_out;

    char* w = (char*)d_ws;
    size_t o = 0;
    auto carve = [&](size_t bytes) -> void* {
        void* p = w + o;
        o = (o + bytes + 255) & ~(size_t)255;
        return p;
    };
    unsigned long long* packed = (unsigned long long*)carve((size_t)N_NODES * 8);
    float* pp   = (float*)carve((size_t)PSLOTS * G_GRAPHS * 4);
    char*  zero_end = w + o;                      // packed + pp span
    int*      cnt  = (int*)     carve((size_t)N_NODES * 4);
    float*    dinv = (float*)   carve((size_t)N_NODES * 4);
    int*      offs = (int*)     carve((size_t)N_NODES * 4);
    int*      part = (int*)     carve(64 * 4);
    uint16_t* seq  = (uint16_t*)carve((size_t)N_EDGES * 2);
    int2*     csr  = (int2*)    carve((size_t)NTOT * 8);
    uint32_t* t    = (uint32_t*)carve((size_t)N_NODES * 64 * 4);   // bf16x2
    uint32_t* hb   = (uint32_t*)carve((size_t)N_NODES * 64 * 4);   // bf16x2
    uint32_t* xb   = (uint32_t*)carve((size_t)N_NODES * 64 * 4);   // bf16x2
    (void)ws_size; (void)in_sizes; (void)n_in; (void)out_size;

    hipMemsetAsync(packed, 0, (size_t)(zero_end - (char*)packed), stream);

    k_deg_cnt<<<(N_EDGES + 255) / 256, 256, 0, stream>>>(ei, ew, packed, seq);
    k_cvt<<<(N_NODES * 64 + 255) / 256, 256, 0, stream>>>(x, xb);
    k_dinv<<<(N_NODES + 255) / 256, 256, 0, stream>>>(packed, cnt, dinv);
    k_scan1<<<SCAN_NB, 256, 0, stream>>>(cnt, part);
    k_scan2<<<1, 64, 0, stream>>>(part);
    k_scan3<<<SCAN_NB, 256, 0, stream>>>(cnt, part, offs);
    k_fill<<<(NTOT + 255) / 256, 256, 0, stream>>>(ei, ew, dinv, offs, cnt, seq, csr);

    k_transform<<<512, 256, 0, stream>>>((const uint16_t*)xb, W1, t);
    k_aggregate<0><<<N_NODES / 4, 256, 0, stream>>>(t, offs, cnt, csr, b1, hb, lw, bat, pp);
    k_transform<<<512, 256, 0, stream>>>((const uint16_t*)hb, W2, t);
    k_aggregate<0><<<N_NODES / 4, 256, 0, stream>>>(t, offs, cnt, csr, b2, hb, lw, bat, pp);
    k_transform<<<512, 256, 0, stream>>>((const uint16_t*)hb, W3, t);
    k_aggregate<1><<<N_NODES / 4, 256, 0, stream>>>(t, offs, cnt, csr, b3, nullptr, lw, bat, pp);

    k_final<<<1, G_GRAPHS, 0, stream>>>(pp, bat, lb, out);
}

// Round 8
// 539.899 us; speedup vs baseline: 3.9319x; 1.2605x over previous
//
#include <hip/hip_runtime.h>
#include <stdint.h>

#define N_NODES 100000
#define N_EDGES 1600000
#define HDIM    128
#define G_GRAPHS 64
#define NTOT (N_EDGES + N_NODES)
#define SCAN_NB ((N_NODES + 2047) / 2048)   // 49
#define PSLOTS 64
#define NSTRIPS (N_NODES / 16)              // 6250

static_assert(N_NODES % 16 == 0, "tile");
static_assert(SCAN_NB <= 64, "scan2 single wave");

typedef __attribute__((ext_vector_type(8))) short bf16x8;
typedef __attribute__((ext_vector_type(4))) float f32x4;

__device__ __forceinline__ float bf_lo(uint32_t u) { return __uint_as_float(u << 16); }
__device__ __forceinline__ float bf_hi(uint32_t u) { return __uint_as_float(u & 0xffff0000u); }
__device__ __forceinline__ uint32_t f2bf(float x) {            // RNE f32->bf16
    uint32_t b = __float_as_uint(x);
    return (b + 0x7FFFu + ((b >> 16) & 1u)) >> 16;
}
__device__ __forceinline__ uint32_t pack2(float lo, float hi) {
    return f2bf(lo) | (f2bf(hi) << 16);
}

#define FXSCALE 1099511627776.0f   // 2^40

// ---- one u64 atomic per edge: high16 = count, low48 = fixed-point weight sum ----
__global__ void k_deg_cnt(const int* __restrict__ ei, const float* __restrict__ ew,
                          unsigned long long* __restrict__ packed, uint16_t* __restrict__ seq) {
    int e = blockIdx.x * 256 + threadIdx.x;
    if (e >= N_EDGES) return;
    int dst = ei[N_EDGES + e];
    unsigned long long pk = (1ULL << 48) | (unsigned long long)(ew[e] * FXSCALE);
    unsigned long long old = atomicAdd(&packed[dst], pk);
    seq[e] = (uint16_t)(old >> 48);
}

// ---- unpack: cnt, dinv = rsqrt(deg + 1) ----
__global__ void k_dinv(const unsigned long long* __restrict__ packed,
                       int* __restrict__ cnt, float* __restrict__ dinv) {
    int i = blockIdx.x * 256 + threadIdx.x;
    if (i >= N_NODES) return;
    unsigned long long pk = packed[i];
    cnt[i] = (int)(pk >> 48);
    float deg = (float)(pk & ((1ULL << 48) - 1)) * (1.0f / FXSCALE);
    dinv[i] = 1.0f / sqrtf(deg + 1.0f);
}

// ---- x f32 -> bf16x2 packed ----
__global__ void k_cvt(const float* __restrict__ x, uint32_t* __restrict__ xb) {
    int i = blockIdx.x * 256 + threadIdx.x;
    if (i >= N_NODES * 64) return;
    float2 v = ((const float2*)x)[i];
    xb[i] = pack2(v.x, v.y);
}

// ---- exclusive scan of (cnt[i]+1), 3 phases ----
__global__ void k_scan1(const int* __restrict__ cnt, int* __restrict__ partial) {
    int tid = threadIdx.x;
    int base = blockIdx.x * 2048 + tid * 8;
    int s = 0;
#pragma unroll
    for (int j = 0; j < 8; j++) {
        int i = base + j;
        if (i < N_NODES) s += cnt[i] + 1;
    }
    for (int off = 32; off; off >>= 1) s += __shfl_down(s, off);
    __shared__ int sw[4];
    if ((tid & 63) == 0) sw[tid >> 6] = s;
    __syncthreads();
    if (tid == 0) partial[blockIdx.x] = sw[0] + sw[1] + sw[2] + sw[3];
}

__global__ void k_scan2(int* __restrict__ partial) {
    int lane = threadIdx.x;
    int v = (lane < SCAN_NB) ? partial[lane] : 0;
    int orig = v;
    for (int off = 1; off < 64; off <<= 1) {
        int u = __shfl_up(v, off);
        if (lane >= off) v += u;
    }
    if (lane < SCAN_NB) partial[lane] = v - orig;   // exclusive
}

__global__ void k_scan3(const int* __restrict__ cnt, const int* __restrict__ partial,
                        int* __restrict__ offs) {
    int tid = threadIdx.x;
    int base = blockIdx.x * 2048 + tid * 8;
    int vals[8];
    int tsum = 0;
#pragma unroll
    for (int j = 0; j < 8; j++) {
        int i = base + j;
        vals[j] = (i < N_NODES) ? cnt[i] + 1 : 0;
        tsum += vals[j];
    }
    __shared__ int s[256];
    s[tid] = tsum;
    __syncthreads();
    for (int off = 1; off < 256; off <<= 1) {
        int v = 0;
        if (tid >= off) v = s[tid - off];
        __syncthreads();
        s[tid] += v;
        __syncthreads();
    }
    int run = partial[blockIdx.x] + s[tid] - tsum;
#pragma unroll
    for (int j = 0; j < 8; j++) {
        int i = base + j;
        if (i < N_NODES) offs[i] = run;
        run += vals[j];
    }
}

// ---- fill CSR (grouped by dst) — no atomics: slot from precomputed seq ----
__global__ void k_fill(const int* __restrict__ ei, const float* __restrict__ ew,
                       const float* __restrict__ dinv, const int* __restrict__ offs,
                       const int* __restrict__ cnt, const uint16_t* __restrict__ seq,
                       int2* __restrict__ csr) {
    int e = blockIdx.x * 256 + threadIdx.x;
    if (e < N_EDGES) {
        int src = ei[e];
        int dst = ei[N_EDGES + e];
        float nrm = dinv[src] * ew[e] * dinv[dst];
        int p = offs[dst] + (int)seq[e];
        csr[p] = make_int2(src, __float_as_int(nrm));
    } else if (e < NTOT) {
        int i = e - N_EDGES;
        float d = dinv[i];
        int p = offs[i] + cnt[i];
        csr[p] = make_int2(i, __float_as_int(d * d));
    }
}

// ---- MFMA transform: t = h @ W, bf16 in/out, f32 accumulate ----
__global__ __launch_bounds__(256) void k_transform(const uint16_t* __restrict__ hb,
                                                   const float* __restrict__ Wg,
                                                   uint32_t* __restrict__ t) {
    __shared__ uint16_t Wf[16384];    // 32 KB, frag-order bf16
    int tid = threadIdx.x;
    for (int idx = tid; idx < 16384; idx += 256) {
        int k = idx >> 7, n = idx & 127;
        int kc = k >> 5, kq = (k >> 3) & 3, j = k & 7;
        int nt = n >> 4, nl = n & 15;
        Wf[(((kc * 8 + nt) * 64) + kq * 16 + nl) * 8 + j] = (uint16_t)f2bf(Wg[idx]);
    }
    __syncthreads();
    const bf16x8* Wfrag = (const bf16x8*)Wf;
    int lane = tid & 63;
    int quad = lane >> 4;
    int mrow = lane & 15;
    int gwave = blockIdx.x * 4 + (tid >> 6);
    int nwaves = gridDim.x * 4;
    for (int strip = gwave; strip < NSTRIPS; strip += nwaves) {
        const uint16_t* hrow = hb + ((size_t)(strip * 16 + mrow)) * 128 + quad * 8;
        bf16x8 A0 = *(const bf16x8*)(hrow);
        bf16x8 A1 = *(const bf16x8*)(hrow + 32);
        bf16x8 A2 = *(const bf16x8*)(hrow + 64);
        bf16x8 A3 = *(const bf16x8*)(hrow + 96);
        f32x4 acc[8];
#pragma unroll
        for (int nt = 0; nt < 8; nt++) {
            f32x4 a = {0.f, 0.f, 0.f, 0.f};
            a = __builtin_amdgcn_mfma_f32_16x16x32_bf16(A0, Wfrag[(0 * 8 + nt) * 64 + lane], a, 0, 0, 0);
            a = __builtin_amdgcn_mfma_f32_16x16x32_bf16(A1, Wfrag[(1 * 8 + nt) * 64 + lane], a, 0, 0, 0);
            a = __builtin_amdgcn_mfma_f32_16x16x32_bf16(A2, Wfrag[(2 * 8 + nt) * 64 + lane], a, 0, 0, 0);
            a = __builtin_amdgcn_mfma_f32_16x16x32_bf16(A3, Wfrag[(3 * 8 + nt) * 64 + lane], a, 0, 0, 0);
            acc[nt] = a;
        }
#pragma unroll
        for (int nt = 0; nt < 8; nt++) {
#pragma unroll
            for (int r = 0; r < 4; r++) {
                float v = acc[nt][r];
                float nb = __shfl_xor(v, 1);
                if (!(lane & 1)) {
                    int orow = strip * 16 + quad * 4 + r;
                    int oc = (nt * 16 + mrow) >> 1;
                    t[(size_t)orow * 64 + oc] = pack2(v, nb);
                }
            }
        }
    }
}

// ---- aggregation: wave per node; 8 independent gathers in flight (MLP) ----
template <int POOL>
__global__ void k_aggregate(const uint32_t* __restrict__ t, const int* __restrict__ offs,
                            const int* __restrict__ cnt, const int2* __restrict__ csr,
                            const float* __restrict__ bias, uint32_t* __restrict__ hout,
                            const float* __restrict__ lw, const int* __restrict__ batch,
                            float* __restrict__ pp) {
    int tid = threadIdx.x;
    int node = blockIdx.x * 4 + (tid >> 6);
    int lane = tid & 63;
    if (node >= N_NODES) return;
    int beg = offs[node];
    int num = cnt[node] + 1;
    float ax = 0.f, ay = 0.f;
    for (int base = 0; base < num; base += 64) {
        int rem = num - base; if (rem > 64) rem = 64;
        int2 my = make_int2(0, 0);
        if (lane < rem) my = csr[beg + base + lane];
        int   msrc = my.x;
        float mw   = __int_as_float(my.y);
        int j = 0;
        for (; j + 8 <= rem; j += 8) {
            int s0 = __shfl(msrc, j + 0), s1 = __shfl(msrc, j + 1);
            int s2 = __shfl(msrc, j + 2), s3 = __shfl(msrc, j + 3);
            int s4 = __shfl(msrc, j + 4), s5 = __shfl(msrc, j + 5);
            int s6 = __shfl(msrc, j + 6), s7 = __shfl(msrc, j + 7);
            float w0 = __shfl(mw, j + 0), w1 = __shfl(mw, j + 1);
            float w2 = __shfl(mw, j + 2), w3 = __shfl(mw, j + 3);
            float w4 = __shfl(mw, j + 4), w5 = __shfl(mw, j + 5);
            float w6 = __shfl(mw, j + 6), w7 = __shfl(mw, j + 7);
            uint32_t v0 = t[(size_t)s0 * 64 + lane];
            uint32_t v1 = t[(size_t)s1 * 64 + lane];
            uint32_t v2 = t[(size_t)s2 * 64 + lane];
            uint32_t v3 = t[(size_t)s3 * 64 + lane];
            uint32_t v4 = t[(size_t)s4 * 64 + lane];
            uint32_t v5 = t[(size_t)s5 * 64 + lane];
            uint32_t v6 = t[(size_t)s6 * 64 + lane];
            uint32_t v7 = t[(size_t)s7 * 64 + lane];
            ax += w0 * bf_lo(v0); ay += w0 * bf_hi(v0);
            ax += w1 * bf_lo(v1); ay += w1 * bf_hi(v1);
            ax += w2 * bf_lo(v2); ay += w2 * bf_hi(v2);
            ax += w3 * bf_lo(v3); ay += w3 * bf_hi(v3);
            ax += w4 * bf_lo(v4); ay += w4 * bf_hi(v4);
            ax += w5 * bf_lo(v5); ay += w5 * bf_hi(v5);
            ax += w6 * bf_lo(v6); ay += w6 * bf_hi(v6);
            ax += w7 * bf_lo(v7); ay += w7 * bf_hi(v7);
        }
        for (; j < rem; j++) {
            int   src = __shfl(msrc, j);
            float w   = __shfl(mw, j);
            uint32_t v = t[(size_t)src * 64 + lane];
            ax += w * bf_lo(v);
            ay += w * bf_hi(v);
        }
    }
    float2 bb = ((const float2*)bias)[lane];
    ax = fmaxf(ax + bb.x, 0.f);
    ay = fmaxf(ay + bb.y, 0.f);
    if (POOL) {
        float2 wv = ((const float2*)lw)[lane];
        float d = ax * wv.x + ay * wv.y;
        for (int off = 32; off; off >>= 1) d += __shfl_down(d, off);
        if (lane == 0)
            atomicAdd(&pp[(blockIdx.x & (PSLOTS - 1)) * G_GRAPHS + batch[node]], d);
    } else {
        hout[(size_t)node * 64 + lane] = pack2(ax, ay);
    }
}

// ---- final: out[g] = (sum over slots)/cnt_g + lb ----
__global__ void k_final(const float* __restrict__ pp, const int* __restrict__ batch,
                        const float* __restrict__ lb, float* __restrict__ out) {
    int g = threadIdx.x;   // 64 threads
    float s = 0.f;
#pragma unroll
    for (int k = 0; k < PSLOTS; k++) s += pp[k * G_GRAPHS + g];
    int lo = 0, hi = N_NODES;
    while (lo < hi) { int m = (lo + hi) >> 1; if (batch[m] < g) lo = m + 1; else hi = m; }
    int beg = lo;
    hi = N_NODES;
    while (lo < hi) { int m = (lo + hi) >> 1; if (batch[m] < g + 1) lo = m + 1; else hi = m; }
    float c = fmaxf((float)(lo - beg), 1.0f);
    out[g] = s / c + lb[0];
}

extern "C" void kernel_launch(void* const* d_in, const int* in_sizes, int n_in,
                              void* d_out, int out_size, void* d_ws, size_t ws_size,
                              hipStream_t stream) {
    const float* x   = (const float*)d_in[0];
    const float* ew  = (const float*)d_in[1];
    const int*   ei  = (const int*)d_in[2];
    const int*   bat = (const int*)d_in[3];
    const float* W1  = (const float*)d_in[4];
    const float* b1  = (const float*)d_in[5];
    const float* W2  = (const float*)d_in[6];
    const float* b2  = (const float*)d_in[7];
    const float* W3  = (const float*)d_in[8];
    const float* b3  = (const float*)d_in[9];
    const float* lw  = (const float*)d_in[10];
    const float* lb  = (const float*)d_in[11];
    float* out = (float*)d_out;

    char* w = (char*)d_ws;
    size_t o = 0;
    auto carve = [&](size_t bytes) -> void* {
        void* p = w + o;
        o = (o + bytes + 255) & ~(size_t)255;
        return p;
    };
    unsigned long long* packed = (unsigned long long*)carve((size_t)N_NODES * 8);
    float* pp   = (float*)carve((size_t)PSLOTS * G_GRAPHS * 4);
    char*  zero_end = w + o;                      // packed + pp span
    int*      cnt  = (int*)     carve((size_t)N_NODES * 4);
    float*    dinv = (float*)   carve((size_t)N_NODES * 4);
    int*      offs = (int*)     carve((size_t)N_NODES * 4);
    int*      part = (int*)     carve(64 * 4);
    uint16_t* seq  = (uint16_t*)carve((size_t)N_EDGES * 2);
    int2*     csr  = (int2*)    carve((size_t)NTOT * 8);
    uint32_t* t    = (uint32_t*)carve((size_t)N_NODES * 64 * 4);   // bf16x2
    uint32_t* hb   = (uint32_t*)carve((size_t)N_NODES * 64 * 4);   // bf16x2
    uint32_t* xb   = (uint32_t*)carve((size_t)N_NODES * 64 * 4);   // bf16x2
    (void)ws_size; (void)in_sizes; (void)n_in; (void)out_size;

    hipMemsetAsync(packed, 0, (size_t)(zero_end - (char*)packed), stream);

    k_deg_cnt<<<(N_EDGES + 255) / 256, 256, 0, stream>>>(ei, ew, packed, seq);
    k_cvt<<<(N_NODES * 64 + 255) / 256, 256, 0, stream>>>(x, xb);
    k_dinv<<<(N_NODES + 255) / 256, 256, 0, stream>>>(packed, cnt, dinv);
    k_scan1<<<SCAN_NB, 256, 0, stream>>>(cnt, part);
    k_scan2<<<1, 64, 0, stream>>>(part);
    k_scan3<<<SCAN_NB, 256, 0, stream>>>(cnt, part, offs);
    k_fill<<<(NTOT + 255) / 256, 256, 0, stream>>>(ei, ew, dinv, offs, cnt, seq, csr);

    k_transform<<<512, 256, 0, stream>>>((const uint16_t*)xb, W1, t);
    k_aggregate<0><<<N_NODES / 4, 256, 0, stream>>>(t, offs, cnt, csr, b1, hb, lw, bat, pp);
    k_transform<<<512, 256, 0, stream>>>((const uint16_t*)hb, W2, t);
    k_aggregate<0><<<N_NODES / 4, 256, 0, stream>>>(t, offs, cnt, csr, b2, hb, lw, bat, pp);
    k_transform<<<512, 256, 0, stream>>>((const uint16_t*)hb, W3, t);
    k_aggregate<1><<<N_NODES / 4, 256, 0, stream>>>(t, offs, cnt, csr, b3, nullptr, lw, bat, pp);

    k_final<<<1, G_GRAPHS, 0, stream>>>(pp, bat, lb, out);
}

// Round 9
// 481.477 us; speedup vs baseline: 4.4090x; 1.1213x over previous
//
#include <hip/hip_runtime.h>
#include <stdint.h>

#define N_NODES 100000
#define N_EDGES 1600000
#define HDIM    128
#define G_GRAPHS 64
#define NTOT (N_EDGES + N_NODES)
#define SCAN_NB ((N_NODES + 2047) / 2048)   // 49
#define PSLOTS 64
#define NSTRIPS (N_NODES / 16)              // 6250

static_assert(N_NODES % 16 == 0, "tile");
static_assert(SCAN_NB <= 64, "scan2 single wave");

typedef __attribute__((ext_vector_type(8))) short bf16x8;
typedef __attribute__((ext_vector_type(4))) float f32x4;
typedef __attribute__((ext_vector_type(2))) float f32x2;

__device__ __forceinline__ float bf_lo(uint32_t u) { return __uint_as_float(u << 16); }
__device__ __forceinline__ float bf_hi(uint32_t u) { return __uint_as_float(u & 0xffff0000u); }
__device__ __forceinline__ uint32_t f2bf(float x) {            // RNE f32->bf16
    uint32_t b = __float_as_uint(x);
    return (b + 0x7FFFu + ((b >> 16) & 1u)) >> 16;
}
__device__ __forceinline__ uint32_t pack2(float lo, float hi) {
    return f2bf(lo) | (f2bf(hi) << 16);
}

#define FXSCALE 1099511627776.0f   // 2^40

// ---- one u64 atomic per edge: high16 = count, low48 = fixed-point weight sum ----
__global__ void k_deg_cnt(const int* __restrict__ ei, const float* __restrict__ ew,
                          unsigned long long* __restrict__ packed, uint16_t* __restrict__ seq) {
    int e = blockIdx.x * 256 + threadIdx.x;
    if (e >= N_EDGES) return;
    int dst = ei[N_EDGES + e];
    unsigned long long pk = (1ULL << 48) | (unsigned long long)(ew[e] * FXSCALE);
    unsigned long long old = atomicAdd(&packed[dst], pk);
    seq[e] = (uint16_t)(old >> 48);
}

// ---- unpack: cnt, dinv = rsqrt(deg + 1) ----
__global__ void k_dinv(const unsigned long long* __restrict__ packed,
                       int* __restrict__ cnt, float* __restrict__ dinv) {
    int i = blockIdx.x * 256 + threadIdx.x;
    if (i >= N_NODES) return;
    unsigned long long pk = packed[i];
    cnt[i] = (int)(pk >> 48);
    float deg = (float)(pk & ((1ULL << 48) - 1)) * (1.0f / FXSCALE);
    dinv[i] = 1.0f / sqrtf(deg + 1.0f);
}

// ---- exclusive scan of (cnt[i]+1), 3 phases ----
__global__ void k_scan1(const int* __restrict__ cnt, int* __restrict__ partial) {
    int tid = threadIdx.x;
    int base = blockIdx.x * 2048 + tid * 8;
    int s = 0;
#pragma unroll
    for (int j = 0; j < 8; j++) {
        int i = base + j;
        if (i < N_NODES) s += cnt[i] + 1;
    }
    for (int off = 32; off; off >>= 1) s += __shfl_down(s, off);
    __shared__ int sw[4];
    if ((tid & 63) == 0) sw[tid >> 6] = s;
    __syncthreads();
    if (tid == 0) partial[blockIdx.x] = sw[0] + sw[1] + sw[2] + sw[3];
}

__global__ void k_scan2(int* __restrict__ partial) {
    int lane = threadIdx.x;
    int v = (lane < SCAN_NB) ? partial[lane] : 0;
    int orig = v;
    for (int off = 1; off < 64; off <<= 1) {
        int u = __shfl_up(v, off);
        if (lane >= off) v += u;
    }
    if (lane < SCAN_NB) partial[lane] = v - orig;   // exclusive
}

__global__ void k_scan3(const int* __restrict__ cnt, const int* __restrict__ partial,
                        int* __restrict__ offs) {
    int tid = threadIdx.x;
    int base = blockIdx.x * 2048 + tid * 8;
    int vals[8];
    int tsum = 0;
#pragma unroll
    for (int j = 0; j < 8; j++) {
        int i = base + j;
        vals[j] = (i < N_NODES) ? cnt[i] + 1 : 0;
        tsum += vals[j];
    }
    __shared__ int s[256];
    s[tid] = tsum;
    __syncthreads();
    for (int off = 1; off < 256; off <<= 1) {
        int v = 0;
        if (tid >= off) v = s[tid - off];
        __syncthreads();
        s[tid] += v;
        __syncthreads();
    }
    int run = partial[blockIdx.x] + s[tid] - tsum;
#pragma unroll
    for (int j = 0; j < 8; j++) {
        int i = base + j;
        if (i < N_NODES) offs[i] = run;
        run += vals[j];
    }
}

// ---- fill CSR (grouped by dst) — no atomics: slot from precomputed seq ----
__global__ void k_fill(const int* __restrict__ ei, const float* __restrict__ ew,
                       const float* __restrict__ dinv, const int* __restrict__ offs,
                       const int* __restrict__ cnt, const uint16_t* __restrict__ seq,
                       int2* __restrict__ csr) {
    int e = blockIdx.x * 256 + threadIdx.x;
    if (e < N_EDGES) {
        int src = ei[e];
        int dst = ei[N_EDGES + e];
        float nrm = dinv[src] * ew[e] * dinv[dst];
        int p = offs[dst] + (int)seq[e];
        csr[p] = make_int2(src, __float_as_int(nrm));
    } else if (e < NTOT) {
        int i = e - N_EDGES;
        float d = dinv[i];
        int p = offs[i] + cnt[i];
        csr[p] = make_int2(i, __float_as_int(d * d));
    }
}

__device__ __forceinline__ bf16x8 load_row_f32(const float* p) {
    float4 a = ((const float4*)p)[0];
    float4 b = ((const float4*)p)[1];
    union { uint32_t u[4]; bf16x8 v; } c;
    c.u[0] = pack2(a.x, a.y); c.u[1] = pack2(a.z, a.w);
    c.u[2] = pack2(b.x, b.y); c.u[3] = pack2(b.z, b.w);
    return c.v;
}

// ---- MFMA transform: t = h @ W; input bf16 (or f32 for layer 1), output fp8 ----
// A-frag: A[m=lane&15][k=quad*8+j]; B-frag pre-swizzled in LDS; D: col=lane&15,
// row=quad*4+reg. Epilogue packs 4 cols -> dword of e4m3 via HW cvt.
template <int F32IN>
__global__ __launch_bounds__(256) void k_transform(const void* __restrict__ hin,
                                                   const float* __restrict__ Wg,
                                                   uint32_t* __restrict__ t) {
    __shared__ uint16_t Wf[16384];    // 32 KB, frag-order bf16
    int tid = threadIdx.x;
    for (int idx = tid; idx < 16384; idx += 256) {
        int k = idx >> 7, n = idx & 127;
        int kc = k >> 5, kq = (k >> 3) & 3, j = k & 7;
        int nt = n >> 4, nl = n & 15;
        Wf[(((kc * 8 + nt) * 64) + kq * 16 + nl) * 8 + j] = (uint16_t)f2bf(Wg[idx]);
    }
    __syncthreads();
    const bf16x8* Wfrag = (const bf16x8*)Wf;
    int lane = tid & 63;
    int quad = lane >> 4;
    int mrow = lane & 15;
    int gwave = blockIdx.x * 4 + (tid >> 6);
    int nwaves = gridDim.x * 4;
    for (int strip = gwave; strip < NSTRIPS; strip += nwaves) {
        bf16x8 A0, A1, A2, A3;
        if (F32IN) {
            const float* hrow = (const float*)hin + ((size_t)(strip * 16 + mrow)) * 128 + quad * 8;
            A0 = load_row_f32(hrow);
            A1 = load_row_f32(hrow + 32);
            A2 = load_row_f32(hrow + 64);
            A3 = load_row_f32(hrow + 96);
        } else {
            const uint16_t* hrow = (const uint16_t*)hin + ((size_t)(strip * 16 + mrow)) * 128 + quad * 8;
            A0 = *(const bf16x8*)(hrow);
            A1 = *(const bf16x8*)(hrow + 32);
            A2 = *(const bf16x8*)(hrow + 64);
            A3 = *(const bf16x8*)(hrow + 96);
        }
        f32x4 acc[8];
#pragma unroll
        for (int nt = 0; nt < 8; nt++) {
            f32x4 a = {0.f, 0.f, 0.f, 0.f};
            a = __builtin_amdgcn_mfma_f32_16x16x32_bf16(A0, Wfrag[(0 * 8 + nt) * 64 + lane], a, 0, 0, 0);
            a = __builtin_amdgcn_mfma_f32_16x16x32_bf16(A1, Wfrag[(1 * 8 + nt) * 64 + lane], a, 0, 0, 0);
            a = __builtin_amdgcn_mfma_f32_16x16x32_bf16(A2, Wfrag[(2 * 8 + nt) * 64 + lane], a, 0, 0, 0);
            a = __builtin_amdgcn_mfma_f32_16x16x32_bf16(A3, Wfrag[(3 * 8 + nt) * 64 + lane], a, 0, 0, 0);
            acc[nt] = a;
        }
#pragma unroll
        for (int nt = 0; nt < 8; nt++) {
#pragma unroll
            for (int r = 0; r < 4; r++) {
                float v = acc[nt][r];
                float nb = __shfl_xor(v, 1);
                int s16 = __builtin_amdgcn_cvt_pk_fp8_f32(v, nb, 0, false); // 2x e4m3
                int hi  = __shfl_xor(s16, 2);
                if (!(lane & 3)) {
                    int orow = strip * 16 + quad * 4 + r;
                    int oc = (nt * 16 + mrow) >> 2;   // dword col 0..31
                    t[(size_t)orow * 32 + oc] = (uint32_t)(s16 & 0xffff) | ((uint32_t)hi << 16);
                }
            }
        }
    }
}

// ---- aggregation: wave per node; lane gathers ushort (2x e4m3) per edge ----
template <int POOL>
__global__ void k_aggregate(const uint16_t* __restrict__ t, const int* __restrict__ offs,
                            const int* __restrict__ cnt, const int2* __restrict__ csr,
                            const float* __restrict__ bias, uint32_t* __restrict__ hout,
                            const float* __restrict__ lw, const int* __restrict__ batch,
                            float* __restrict__ pp) {
    int tid = threadIdx.x;
    int node = blockIdx.x * 4 + (tid >> 6);
    int lane = tid & 63;
    if (node >= N_NODES) return;
    int beg = offs[node];
    int num = cnt[node] + 1;
    float ax = 0.f, ay = 0.f;
    for (int base = 0; base < num; base += 64) {
        int rem = num - base; if (rem > 64) rem = 64;
        int2 my = make_int2(0, 0);
        if (lane < rem) my = csr[beg + base + lane];
        int   msrc = my.x;
        float mw   = __int_as_float(my.y);
        int j = 0;
        for (; j + 8 <= rem; j += 8) {
            int s0 = __shfl(msrc, j + 0), s1 = __shfl(msrc, j + 1);
            int s2 = __shfl(msrc, j + 2), s3 = __shfl(msrc, j + 3);
            int s4 = __shfl(msrc, j + 4), s5 = __shfl(msrc, j + 5);
            int s6 = __shfl(msrc, j + 6), s7 = __shfl(msrc, j + 7);
            float w0 = __shfl(mw, j + 0), w1 = __shfl(mw, j + 1);
            float w2 = __shfl(mw, j + 2), w3 = __shfl(mw, j + 3);
            float w4 = __shfl(mw, j + 4), w5 = __shfl(mw, j + 5);
            float w6 = __shfl(mw, j + 6), w7 = __shfl(mw, j + 7);
            int v0 = t[(size_t)s0 * 64 + lane];
            int v1 = t[(size_t)s1 * 64 + lane];
            int v2 = t[(size_t)s2 * 64 + lane];
            int v3 = t[(size_t)s3 * 64 + lane];
            int v4 = t[(size_t)s4 * 64 + lane];
            int v5 = t[(size_t)s5 * 64 + lane];
            int v6 = t[(size_t)s6 * 64 + lane];
            int v7 = t[(size_t)s7 * 64 + lane];
            f32x2 d0 = __builtin_amdgcn_cvt_pk_f32_fp8(v0, false);
            f32x2 d1 = __builtin_amdgcn_cvt_pk_f32_fp8(v1, false);
            f32x2 d2 = __builtin_amdgcn_cvt_pk_f32_fp8(v2, false);
            f32x2 d3 = __builtin_amdgcn_cvt_pk_f32_fp8(v3, false);
            f32x2 d4 = __builtin_amdgcn_cvt_pk_f32_fp8(v4, false);
            f32x2 d5 = __builtin_amdgcn_cvt_pk_f32_fp8(v5, false);
            f32x2 d6 = __builtin_amdgcn_cvt_pk_f32_fp8(v6, false);
            f32x2 d7 = __builtin_amdgcn_cvt_pk_f32_fp8(v7, false);
            ax += w0 * d0.x; ay += w0 * d0.y;
            ax += w1 * d1.x; ay += w1 * d1.y;
            ax += w2 * d2.x; ay += w2 * d2.y;
            ax += w3 * d3.x; ay += w3 * d3.y;
            ax += w4 * d4.x; ay += w4 * d4.y;
            ax += w5 * d5.x; ay += w5 * d5.y;
            ax += w6 * d6.x; ay += w6 * d6.y;
            ax += w7 * d7.x; ay += w7 * d7.y;
        }
        for (; j < rem; j++) {
            int   src = __shfl(msrc, j);
            float w   = __shfl(mw, j);
            f32x2 d = __builtin_amdgcn_cvt_pk_f32_fp8((int)t[(size_t)src * 64 + lane], false);
            ax += w * d.x;
            ay += w * d.y;
        }
    }
    float2 bb = ((const float2*)bias)[lane];
    ax = fmaxf(ax + bb.x, 0.f);
    ay = fmaxf(ay + bb.y, 0.f);
    if (POOL) {
        float2 wv = ((const float2*)lw)[lane];
        float d = ax * wv.x + ay * wv.y;
        for (int off = 32; off; off >>= 1) d += __shfl_down(d, off);
        if (lane == 0)
            atomicAdd(&pp[(blockIdx.x & (PSLOTS - 1)) * G_GRAPHS + batch[node]], d);
    } else {
        hout[(size_t)node * 64 + lane] = pack2(ax, ay);
    }
}

// ---- final: out[g] = (sum over slots)/cnt_g + lb ----
__global__ void k_final(const float* __restrict__ pp, const int* __restrict__ batch,
                        const float* __restrict__ lb, float* __restrict__ out) {
    int g = threadIdx.x;   // 64 threads
    float s = 0.f;
#pragma unroll
    for (int k = 0; k < PSLOTS; k++) s += pp[k * G_GRAPHS + g];
    int lo = 0, hi = N_NODES;
    while (lo < hi) { int m = (lo + hi) >> 1; if (batch[m] < g) lo = m + 1; else hi = m; }
    int beg = lo;
    hi = N_NODES;
    while (lo < hi) { int m = (lo + hi) >> 1; if (batch[m] < g + 1) lo = m + 1; else hi = m; }
    float c = fmaxf((float)(lo - beg), 1.0f);
    out[g] = s / c + lb[0];
}

extern "C" void kernel_launch(void* const* d_in, const int* in_sizes, int n_in,
                              void* d_out, int out_size, void* d_ws, size_t ws_size,
                              hipStream_t stream) {
    const float* x   = (const float*)d_in[0];
    const float* ew  = (const float*)d_in[1];
    const int*   ei  = (const int*)d_in[2];
    const int*   bat = (const int*)d_in[3];
    const float* W1  = (const float*)d_in[4];
    const float* b1  = (const float*)d_in[5];
    const float* W2  = (const float*)d_in[6];
    const float* b2  = (const float*)d_in[7];
    const float* W3  = (const float*)d_in[8];
    const float* b3  = (const float*)d_in[9];
    const float* lw  = (const float*)d_in[10];
    const float* lb  = (const float*)d_in[11];
    float* out = (float*)d_out;

    char* w = (char*)d_ws;
    size_t o = 0;
    auto carve = [&](size_t bytes) -> void* {
        void* p = w + o;
        o = (o + bytes + 255) & ~(size_t)255;
        return p;
    };
    unsigned long long* packed = (unsigned long long*)carve((size_t)N_NODES * 8);
    float* pp   = (float*)carve((size_t)PSLOTS * G_GRAPHS * 4);
    char*  zero_end = w + o;                      // packed + pp span
    int*      cnt  = (int*)     carve((size_t)N_NODES * 4);
    float*    dinv = (float*)   carve((size_t)N_NODES * 4);
    int*      offs = (int*)     carve((size_t)N_NODES * 4);
    int*      part = (int*)     carve(64 * 4);
    uint16_t* seq  = (uint16_t*)carve((size_t)N_EDGES * 2);
    int2*     csr  = (int2*)    carve((size_t)NTOT * 8);
    uint32_t* t    = (uint32_t*)carve((size_t)N_NODES * 128);      // fp8 rows, 128 B
    uint32_t* hb   = (uint32_t*)carve((size_t)N_NODES * 64 * 4);   // bf16x2
    (void)ws_size; (void)in_sizes; (void)n_in; (void)out_size;

    hipMemsetAsync(packed, 0, (size_t)(zero_end - (char*)packed), stream);

    k_deg_cnt<<<(N_EDGES + 255) / 256, 256, 0, stream>>>(ei, ew, packed, seq);
    k_dinv<<<(N_NODES + 255) / 256, 256, 0, stream>>>(packed, cnt, dinv);
    k_scan1<<<SCAN_NB, 256, 0, stream>>>(cnt, part);
    k_scan2<<<1, 64, 0, stream>>>(part);
    k_scan3<<<SCAN_NB, 256, 0, stream>>>(cnt, part, offs);
    k_fill<<<(NTOT + 255) / 256, 256, 0, stream>>>(ei, ew, dinv, offs, cnt, seq, csr);

    k_transform<1><<<512, 256, 0, stream>>>((const void*)x, W1, t);
    k_aggregate<0><<<N_NODES / 4, 256, 0, stream>>>((const uint16_t*)t, offs, cnt, csr, b1, hb, lw, bat, pp);
    k_transform<0><<<512, 256, 0, stream>>>((const void*)hb, W2, t);
    k_aggregate<0><<<N_NODES / 4, 256, 0, stream>>>((const uint16_t*)t, offs, cnt, csr, b2, hb, lw, bat, pp);
    k_transform<0><<<512, 256, 0, stream>>>((const void*)hb, W3, t);
    k_aggregate<1><<<N_NODES / 4, 256, 0, stream>>>((const uint16_t*)t, offs, cnt, csr, b3, nullptr, lw, bat, pp);

    k_final<<<1, G_GRAPHS, 0, stream>>>(pp, bat, lb, out);
}

// Round 10
// 439.279 us; speedup vs baseline: 4.8326x; 1.0961x over previous
//
#include <hip/hip_runtime.h>
#include <stdint.h>

#define N_NODES 100000
#define N_EDGES 1600000
#define HDIM    128
#define G_GRAPHS 64
#define NTOT (N_EDGES + N_NODES)
#define SCAN_NB ((N_NODES + 2047) / 2048)   // 49
#define PSLOTS 64
#define NSTRIPS (N_NODES / 16)              // 6250
#define NTB 512                              // transform blocks in fused kernel
#define NDB ((N_EDGES + 255) / 256)          // 6250 deg blocks

static_assert(N_NODES % 16 == 0, "tile");
static_assert(N_NODES % 8 == 0, "two nodes per wave");
static_assert(SCAN_NB <= 64, "scan2 single wave");

typedef __attribute__((ext_vector_type(8))) short bf16x8;
typedef __attribute__((ext_vector_type(4))) float f32x4;
typedef __attribute__((ext_vector_type(2))) float f32x2;

__device__ __forceinline__ uint32_t f2bf(float x) {            // RNE f32->bf16
    uint32_t b = __float_as_uint(x);
    return (b + 0x7FFFu + ((b >> 16) & 1u)) >> 16;
}
__device__ __forceinline__ uint32_t pack2(float lo, float hi) {
    return f2bf(lo) | (f2bf(hi) << 16);
}

#define FXSCALE 1099511627776.0f   // 2^40

// ---- unpack: cnt, dinv = rsqrt(deg + 1) ----
__global__ void k_dinv(const unsigned long long* __restrict__ packed,
                       int* __restrict__ cnt, float* __restrict__ dinv) {
    int i = blockIdx.x * 256 + threadIdx.x;
    if (i >= N_NODES) return;
    unsigned long long pk = packed[i];
    cnt[i] = (int)(pk >> 48);
    float deg = (float)(pk & ((1ULL << 48) - 1)) * (1.0f / FXSCALE);
    dinv[i] = 1.0f / sqrtf(deg + 1.0f);
}

// ---- exclusive scan of (cnt[i]+1), 3 phases ----
__global__ void k_scan1(const int* __restrict__ cnt, int* __restrict__ partial) {
    int tid = threadIdx.x;
    int base = blockIdx.x * 2048 + tid * 8;
    int s = 0;
#pragma unroll
    for (int j = 0; j < 8; j++) {
        int i = base + j;
        if (i < N_NODES) s += cnt[i] + 1;
    }
    for (int off = 32; off; off >>= 1) s += __shfl_down(s, off);
    __shared__ int sw[4];
    if ((tid & 63) == 0) sw[tid >> 6] = s;
    __syncthreads();
    if (tid == 0) partial[blockIdx.x] = sw[0] + sw[1] + sw[2] + sw[3];
}

__global__ void k_scan2(int* __restrict__ partial) {
    int lane = threadIdx.x;
    int v = (lane < SCAN_NB) ? partial[lane] : 0;
    int orig = v;
    for (int off = 1; off < 64; off <<= 1) {
        int u = __shfl_up(v, off);
        if (lane >= off) v += u;
    }
    if (lane < SCAN_NB) partial[lane] = v - orig;   // exclusive
}

__global__ void k_scan3(const int* __restrict__ cnt, const int* __restrict__ partial,
                        int* __restrict__ offs) {
    int tid = threadIdx.x;
    int base = blockIdx.x * 2048 + tid * 8;
    int vals[8];
    int tsum = 0;
#pragma unroll
    for (int j = 0; j < 8; j++) {
        int i = base + j;
        vals[j] = (i < N_NODES) ? cnt[i] + 1 : 0;
        tsum += vals[j];
    }
    __shared__ int s[256];
    s[tid] = tsum;
    __syncthreads();
    for (int off = 1; off < 256; off <<= 1) {
        int v = 0;
        if (tid >= off) v = s[tid - off];
        __syncthreads();
        s[tid] += v;
        __syncthreads();
    }
    int run = partial[blockIdx.x] + s[tid] - tsum;
#pragma unroll
    for (int j = 0; j < 8; j++) {
        int i = base + j;
        if (i < N_NODES) offs[i] = run;
        run += vals[j];
    }
}

// ---- fill CSR (grouped by dst) — no atomics: slot from precomputed seq ----
__global__ void k_fill(const int* __restrict__ ei, const float* __restrict__ ew,
                       const float* __restrict__ dinv, const int* __restrict__ offs,
                       const int* __restrict__ cnt, const uint16_t* __restrict__ seq,
                       int2* __restrict__ csr) {
    int e = blockIdx.x * 256 + threadIdx.x;
    if (e < N_EDGES) {
        int src = ei[e];
        int dst = ei[N_EDGES + e];
        float nrm = dinv[src] * ew[e] * dinv[dst];
        int p = offs[dst] + (int)seq[e];
        csr[p] = make_int2(src, __float_as_int(nrm));
    } else if (e < NTOT) {
        int i = e - N_EDGES;
        float d = dinv[i];
        int p = offs[i] + cnt[i];
        csr[p] = make_int2(i, __float_as_int(d * d));
    }
}

__device__ __forceinline__ bf16x8 load_row_f32(const float* p) {
    float4 a = ((const float4*)p)[0];
    float4 b = ((const float4*)p)[1];
    union { uint32_t u[4]; bf16x8 v; } c;
    c.u[0] = pack2(a.x, a.y); c.u[1] = pack2(a.z, a.w);
    c.u[2] = pack2(b.x, b.y); c.u[3] = pack2(b.z, b.w);
    return c.v;
}

// ---- transform body: t = h @ W (bf16 MFMA, fp8 output), strip-strided ----
template <int F32IN>
__device__ __forceinline__ void transform_body(int tb, int nTB, int tid,
                                               const void* __restrict__ hin,
                                               const float* __restrict__ Wg,
                                               uint32_t* __restrict__ t,
                                               uint16_t* Wf) {
    for (int idx = tid; idx < 16384; idx += 256) {
        int k = idx >> 7, n = idx & 127;
        int kc = k >> 5, kq = (k >> 3) & 3, j = k & 7;
        int nt = n >> 4, nl = n & 15;
        Wf[(((kc * 8 + nt) * 64) + kq * 16 + nl) * 8 + j] = (uint16_t)f2bf(Wg[idx]);
    }
    __syncthreads();
    const bf16x8* Wfrag = (const bf16x8*)Wf;
    int lane = tid & 63;
    int quad = lane >> 4;
    int mrow = lane & 15;
    int gwave = tb * 4 + (tid >> 6);
    int nwaves = nTB * 4;
    for (int strip = gwave; strip < NSTRIPS; strip += nwaves) {
        bf16x8 A0, A1, A2, A3;
        if (F32IN) {
            const float* hrow = (const float*)hin + ((size_t)(strip * 16 + mrow)) * 128 + quad * 8;
            A0 = load_row_f32(hrow);
            A1 = load_row_f32(hrow + 32);
            A2 = load_row_f32(hrow + 64);
            A3 = load_row_f32(hrow + 96);
        } else {
            const uint16_t* hrow = (const uint16_t*)hin + ((size_t)(strip * 16 + mrow)) * 128 + quad * 8;
            A0 = *(const bf16x8*)(hrow);
            A1 = *(const bf16x8*)(hrow + 32);
            A2 = *(const bf16x8*)(hrow + 64);
            A3 = *(const bf16x8*)(hrow + 96);
        }
        f32x4 acc[8];
#pragma unroll
        for (int nt = 0; nt < 8; nt++) {
            f32x4 a = {0.f, 0.f, 0.f, 0.f};
            a = __builtin_amdgcn_mfma_f32_16x16x32_bf16(A0, Wfrag[(0 * 8 + nt) * 64 + lane], a, 0, 0, 0);
            a = __builtin_amdgcn_mfma_f32_16x16x32_bf16(A1, Wfrag[(1 * 8 + nt) * 64 + lane], a, 0, 0, 0);
            a = __builtin_amdgcn_mfma_f32_16x16x32_bf16(A2, Wfrag[(2 * 8 + nt) * 64 + lane], a, 0, 0, 0);
            a = __builtin_amdgcn_mfma_f32_16x16x32_bf16(A3, Wfrag[(3 * 8 + nt) * 64 + lane], a, 0, 0, 0);
            acc[nt] = a;
        }
#pragma unroll
        for (int nt = 0; nt < 8; nt++) {
#pragma unroll
            for (int r = 0; r < 4; r++) {
                float v = acc[nt][r];
                float nb = __shfl_xor(v, 1);
                int s16 = __builtin_amdgcn_cvt_pk_fp8_f32(v, nb, 0, false); // 2x e4m3
                int hi  = __shfl_xor(s16, 2);
                if (!(lane & 3)) {
                    int orow = strip * 16 + quad * 4 + r;
                    int oc = (nt * 16 + mrow) >> 2;   // dword col 0..31
                    t[(size_t)orow * 32 + oc] = (uint32_t)(s16 & 0xffff) | ((uint32_t)hi << 16);
                }
            }
        }
    }
}

// ---- fused: deg/cnt histogram (atomic-bound) + layer-1 transform (MFMA-bound)
// Heterogeneous grid: every 13th block (up to 512) runs the transform body;
// the other 6250 run the edge histogram. Co-resident waves overlap pipes.
__global__ __launch_bounds__(256) void k_deg_transform(
        const int* __restrict__ ei, const float* __restrict__ ew,
        unsigned long long* __restrict__ packed, uint16_t* __restrict__ seq,
        const float* __restrict__ x, const float* __restrict__ Wg,
        uint32_t* __restrict__ t) {
    __shared__ uint16_t Wf[16384];    // 32 KB (transform blocks only)
    int bi = blockIdx.x;
    int q = bi / 13;
    bool isT = ((bi % 13) == 0) && (q < NTB);
    if (isT) {
        transform_body<1>(q, NTB, threadIdx.x, (const void*)x, Wg, t, Wf);
    } else {
        int nT = (bi + 12) / 13; if (nT > NTB) nT = NTB;
        int db = bi - nT;                       // 0..NDB-1
        int e = db * 256 + threadIdx.x;
        if (e < N_EDGES) {
            int dst = ei[N_EDGES + e];
            unsigned long long pk = (1ULL << 48) | (unsigned long long)(ew[e] * FXSCALE);
            unsigned long long old = atomicAdd(&packed[dst], pk);
            seq[e] = (uint16_t)(old >> 48);
        }
    }
}

// ---- standalone transform for layers 2-3 ----
__global__ __launch_bounds__(256) void k_transform(const void* __restrict__ hin,
                                                   const float* __restrict__ Wg,
                                                   uint32_t* __restrict__ t) {
    __shared__ uint16_t Wf[16384];
    transform_body<0>(blockIdx.x, gridDim.x, threadIdx.x, hin, Wg, t, Wf);
}

// ---- aggregation: 2 nodes per wave (32 lanes each), dword = 4 fp8 channels ----
template <int POOL>
__global__ void k_aggregate(const uint32_t* __restrict__ t, const int* __restrict__ offs,
                            const int* __restrict__ cnt, const int2* __restrict__ csr,
                            const float* __restrict__ bias, uint32_t* __restrict__ hout,
                            const float* __restrict__ lw, const int* __restrict__ batch,
                            float* __restrict__ pp) {
    int tid = threadIdx.x;
    int lane = tid & 63;
    int hl = lane & 31;
    int hb6 = lane & 32;                     // half selector for shfl indexing
    int node = blockIdx.x * 8 + (tid >> 6) * 2 + (lane >> 5);
    int beg = offs[node];
    int num = cnt[node] + 1;
    f32x4 acc = {0.f, 0.f, 0.f, 0.f};
    for (int base = 0; base < num; base += 32) {
        int rem = num - base; if (rem > 32) rem = 32;
        int2 my = make_int2(0, 0);
        if (hl < rem) my = csr[beg + base + hl];
        int   msrc = my.x;
        float mw   = __int_as_float(my.y);
        int j = 0;
        for (; j + 8 <= rem; j += 8) {
            int s0 = __shfl(msrc, hb6 | (j + 0)), s1 = __shfl(msrc, hb6 | (j + 1));
            int s2 = __shfl(msrc, hb6 | (j + 2)), s3 = __shfl(msrc, hb6 | (j + 3));
            int s4 = __shfl(msrc, hb6 | (j + 4)), s5 = __shfl(msrc, hb6 | (j + 5));
            int s6 = __shfl(msrc, hb6 | (j + 6)), s7 = __shfl(msrc, hb6 | (j + 7));
            float w0 = __shfl(mw, hb6 | (j + 0)), w1 = __shfl(mw, hb6 | (j + 1));
            float w2 = __shfl(mw, hb6 | (j + 2)), w3 = __shfl(mw, hb6 | (j + 3));
            float w4 = __shfl(mw, hb6 | (j + 4)), w5 = __shfl(mw, hb6 | (j + 5));
            float w6 = __shfl(mw, hb6 | (j + 6)), w7 = __shfl(mw, hb6 | (j + 7));
            int v0 = t[(size_t)s0 * 32 + hl];
            int v1 = t[(size_t)s1 * 32 + hl];
            int v2 = t[(size_t)s2 * 32 + hl];
            int v3 = t[(size_t)s3 * 32 + hl];
            int v4 = t[(size_t)s4 * 32 + hl];
            int v5 = t[(size_t)s5 * 32 + hl];
            int v6 = t[(size_t)s6 * 32 + hl];
            int v7 = t[(size_t)s7 * 32 + hl];
            f32x2 l0 = __builtin_amdgcn_cvt_pk_f32_fp8(v0, false), h0 = __builtin_amdgcn_cvt_pk_f32_fp8(v0, true);
            f32x2 l1 = __builtin_amdgcn_cvt_pk_f32_fp8(v1, false), h1 = __builtin_amdgcn_cvt_pk_f32_fp8(v1, true);
            f32x2 l2 = __builtin_amdgcn_cvt_pk_f32_fp8(v2, false), h2 = __builtin_amdgcn_cvt_pk_f32_fp8(v2, true);
            f32x2 l3 = __builtin_amdgcn_cvt_pk_f32_fp8(v3, false), h3 = __builtin_amdgcn_cvt_pk_f32_fp8(v3, true);
            f32x2 l4 = __builtin_amdgcn_cvt_pk_f32_fp8(v4, false), h4 = __builtin_amdgcn_cvt_pk_f32_fp8(v4, true);
            f32x2 l5 = __builtin_amdgcn_cvt_pk_f32_fp8(v5, false), h5 = __builtin_amdgcn_cvt_pk_f32_fp8(v5, true);
            f32x2 l6 = __builtin_amdgcn_cvt_pk_f32_fp8(v6, false), h6 = __builtin_amdgcn_cvt_pk_f32_fp8(v6, true);
            f32x2 l7 = __builtin_amdgcn_cvt_pk_f32_fp8(v7, false), h7 = __builtin_amdgcn_cvt_pk_f32_fp8(v7, true);
            acc.x += w0 * l0.x; acc.y += w0 * l0.y; acc.z += w0 * h0.x; acc.w += w0 * h0.y;
            acc.x += w1 * l1.x; acc.y += w1 * l1.y; acc.z += w1 * h1.x; acc.w += w1 * h1.y;
            acc.x += w2 * l2.x; acc.y += w2 * l2.y; acc.z += w2 * h2.x; acc.w += w2 * h2.y;
            acc.x += w3 * l3.x; acc.y += w3 * l3.y; acc.z += w3 * h3.x; acc.w += w3 * h3.y;
            acc.x += w4 * l4.x; acc.y += w4 * l4.y; acc.z += w4 * h4.x; acc.w += w4 * h4.y;
            acc.x += w5 * l5.x; acc.y += w5 * l5.y; acc.z += w5 * h5.x; acc.w += w5 * h5.y;
            acc.x += w6 * l6.x; acc.y += w6 * l6.y; acc.z += w6 * h6.x; acc.w += w6 * h6.y;
            acc.x += w7 * l7.x; acc.y += w7 * l7.y; acc.z += w7 * h7.x; acc.w += w7 * h7.y;
        }
        for (; j < rem; j++) {
            int   src = __shfl(msrc, hb6 | j);
            float w   = __shfl(mw, hb6 | j);
            int v = t[(size_t)src * 32 + hl];
            f32x2 lo = __builtin_amdgcn_cvt_pk_f32_fp8(v, false);
            f32x2 hi = __builtin_amdgcn_cvt_pk_f32_fp8(v, true);
            acc.x += w * lo.x; acc.y += w * lo.y; acc.z += w * hi.x; acc.w += w * hi.y;
        }
    }
    float4 bb = ((const float4*)bias)[hl];
    acc.x = fmaxf(acc.x + bb.x, 0.f);
    acc.y = fmaxf(acc.y + bb.y, 0.f);
    acc.z = fmaxf(acc.z + bb.z, 0.f);
    acc.w = fmaxf(acc.w + bb.w, 0.f);
    if (POOL) {
        float4 wv = ((const float4*)lw)[hl];
        float d = acc.x * wv.x + acc.y * wv.y + acc.z * wv.z + acc.w * wv.w;
        for (int off = 16; off; off >>= 1) d += __shfl_down(d, off);
        if (hl == 0)
            atomicAdd(&pp[(blockIdx.x & (PSLOTS - 1)) * G_GRAPHS + batch[node]], d);
    } else {
        uint2 o2;
        o2.x = pack2(acc.x, acc.y);
        o2.y = pack2(acc.z, acc.w);
        ((uint2*)hout)[(size_t)node * 32 + hl] = o2;
    }
}

// ---- final: out[g] = (sum over slots)/cnt_g + lb ----
__global__ void k_final(const float* __restrict__ pp, const int* __restrict__ batch,
                        const float* __restrict__ lb, float* __restrict__ out) {
    int g = threadIdx.x;   // 64 threads
    float s = 0.f;
#pragma unroll
    for (int k = 0; k < PSLOTS; k++) s += pp[k * G_GRAPHS + g];
    int lo = 0, hi = N_NODES;
    while (lo < hi) { int m = (lo + hi) >> 1; if (batch[m] < g) lo = m + 1; else hi = m; }
    int beg = lo;
    hi = N_NODES;
    while (lo < hi) { int m = (lo + hi) >> 1; if (batch[m] < g + 1) lo = m + 1; else hi = m; }
    float c = fmaxf((float)(lo - beg), 1.0f);
    out[g] = s / c + lb[0];
}

extern "C" void kernel_launch(void* const* d_in, const int* in_sizes, int n_in,
                              void* d_out, int out_size, void* d_ws, size_t ws_size,
                              hipStream_t stream) {
    const float* x   = (const float*)d_in[0];
    const float* ew  = (const float*)d_in[1];
    const int*   ei  = (const int*)d_in[2];
    const int*   bat = (const int*)d_in[3];
    const float* W1  = (const float*)d_in[4];
    const float* b1  = (const float*)d_in[5];
    const float* W2  = (const float*)d_in[6];
    const float* b2  = (const float*)d_in[7];
    const float* W3  = (const float*)d_in[8];
    const float* b3  = (const float*)d_in[9];
    const float* lw  = (const float*)d_in[10];
    const float* lb  = (const float*)d_in[11];
    float* out = (float*)d_out;

    char* w = (char*)d_ws;
    size_t o = 0;
    auto carve = [&](size_t bytes) -> void* {
        void* p = w + o;
        o = (o + bytes + 255) & ~(size_t)255;
        return p;
    };
    unsigned long long* packed = (unsigned long long*)carve((size_t)N_NODES * 8);
    float* pp   = (float*)carve((size_t)PSLOTS * G_GRAPHS * 4);
    char*  zero_end = w + o;                      // packed + pp span
    int*      cnt  = (int*)     carve((size_t)N_NODES * 4);
    float*    dinv = (float*)   carve((size_t)N_NODES * 4);
    int*      offs = (int*)     carve((size_t)N_NODES * 4);
    int*      part = (int*)     carve(64 * 4);
    uint16_t* seq  = (uint16_t*)carve((size_t)N_EDGES * 2);
    int2*     csr  = (int2*)    carve((size_t)NTOT * 8);
    uint32_t* t    = (uint32_t*)carve((size_t)N_NODES * 128);      // fp8 rows, 128 B
    uint32_t* hb   = (uint32_t*)carve((size_t)N_NODES * 64 * 4);   // bf16x2
    (void)ws_size; (void)in_sizes; (void)n_in; (void)out_size;

    hipMemsetAsync(packed, 0, (size_t)(zero_end - (char*)packed), stream);

    // fused: edge histogram (atomic-bound) + layer-1 transform (MFMA-bound)
    k_deg_transform<<<NTB + NDB, 256, 0, stream>>>(ei, ew, packed, seq, x, W1, t);
    k_dinv<<<(N_NODES + 255) / 256, 256, 0, stream>>>(packed, cnt, dinv);
    k_scan1<<<SCAN_NB, 256, 0, stream>>>(cnt, part);
    k_scan2<<<1, 64, 0, stream>>>(part);
    k_scan3<<<SCAN_NB, 256, 0, stream>>>(cnt, part, offs);
    k_fill<<<(NTOT + 255) / 256, 256, 0, stream>>>(ei, ew, dinv, offs, cnt, seq, csr);

    k_aggregate<0><<<N_NODES / 8, 256, 0, stream>>>(t, offs, cnt, csr, b1, hb, lw, bat, pp);
    k_transform<<<512, 256, 0, stream>>>((const void*)hb, W2, t);
    k_aggregate<0><<<N_NODES / 8, 256, 0, stream>>>(t, offs, cnt, csr, b2, hb, lw, bat, pp);
    k_transform<<<512, 256, 0, stream>>>((const void*)hb, W3, t);
    k_aggregate<1><<<N_NODES / 8, 256, 0, stream>>>(t, offs, cnt, csr, b3, nullptr, lw, bat, pp);

    k_final<<<1, G_GRAPHS, 0, stream>>>(pp, bat, lb, out);
}